// Round 1
// 376.072 us; speedup vs baseline: 1.0449x; 1.0449x over previous
//
#include <hip/hip_runtime.h>

#define HIDDEN 2048
#define NQ     1024
#define NCTX   2048
#define NTOT   3072
#define NHEADS 32
#define KVH    8
#define HD     128

typedef __attribute__((ext_vector_type(8))) __bf16 bf16x8;
typedef __attribute__((ext_vector_type(4))) __bf16 bf16x4;
typedef __attribute__((ext_vector_type(4))) float  f32x4;

#define MFMA16(a, b, c) __builtin_amdgcn_mfma_f32_16x16x32_bf16(a, b, c, 0, 0, 0)

// Fixed softmax shift (Cauchy-Schwarz: |q|=1 after folded 1/sqrt(d), |k|=sqrt(128),
// RoPE norm-preserving => s <= 11.4 incl. bf16 rounding).
#define MSTATIC 12.0f

__device__ __forceinline__ void load_lds16(const void* g, void* l) {
    __builtin_amdgcn_global_load_lds(
        (const __attribute__((address_space(1))) unsigned int*)g,
        (__attribute__((address_space(3))) unsigned int*)l, 16, 0, 0);
}

// ---------------------------------------------------------------------------
// z-fused fp32 -> bf16 convert (activations only; weights convert in-GEMM)
// ---------------------------------------------------------------------------
__global__ __launch_bounds__(256) void conv2_f32_bf16(const float* __restrict__ s0,
                                                      __bf16* __restrict__ d0, int n0,
                                                      const float* __restrict__ s1,
                                                      __bf16* __restrict__ d1, int n1) {
    const float* s = blockIdx.y ? s1 : s0;
    __bf16*      d = blockIdx.y ? d1 : d0;
    int          n = blockIdx.y ? n1 : n0;
    int i = blockIdx.x * 256 + threadIdx.x;
    int stride = gridDim.x * 256;
    for (; i < n; i += stride) {
        float4 v = ((const float4*)s)[i];
        bf16x4 o;
        o[0] = (__bf16)v.x; o[1] = (__bf16)v.y;
        o[2] = (__bf16)v.z; o[3] = (__bf16)v.w;
        ((bf16x4*)d)[i] = o;
    }
}

// ---------------------------------------------------------------------------
// 128x128 MFMA GEMM tile body; A bf16 (async global->LDS), B fp32
// (register-staged + converted to bf16 in LDS).
// R8: (1) XOR bank-swizzle on both LDS tiles — 128B rows put all 16 fragment-
//     read lanes of a quad on one 4-bank group (16-way conflict, 1.57e7/disp).
//     As is global_load_lds-written (linear dest mandatory), so the swizzle is
//     applied by pre-swizzling the per-lane GLOBAL source col (rule #21:
//     linear dest + inverse-swz source + swz read; XOR is an involution).
//     Geometry makes the row-XOR lane-constant: (lane>>3)&7 on the store side,
//     n16&7 on the read side — zero per-iteration VALU cost.
// (2) Double-buffered LDS, ONE barrier per K-step: next tile's A (gload_lds)
//     and B (fp32 global->reg) are issued BEFORE compute on the current tile;
//     B's cvt+ds_write lands after compute (T14 issue-early/write-late).
//     LDS 64 KB -> 2 blocks/CU, matching the 640-block grid.
// ---------------------------------------------------------------------------
template <typename OutT>
__device__ __forceinline__ void gemm128_f32b(const __bf16* __restrict__ Ablk,
                                             const float* __restrict__ Bblk,
                                             OutT* __restrict__ Cblk,
                                             int K, int lda, int ldb, int ldc) {
    __shared__ __bf16 As[2][128][64];
    __shared__ __bf16 Bs[2][128][64];

    const int tid  = threadIdx.x;
    const int lane = tid & 63;
    const int w    = tid >> 6;
    const int n16  = lane & 15;
    const int quad = lane >> 4;
    const int wm = (w & 1) * 64;
    const int wn = (w >> 1) * 64;

    f32x4 acc[4][4];
    const f32x4 fzero = {0.f, 0.f, 0.f, 0.f};
#pragma unroll
    for (int i = 0; i < 4; i++)
#pragma unroll
        for (int j = 0; j < 4; j++) acc[i][j] = fzero;

    // A staging: linear LDS dest (wave-linear, required by global_load_lds),
    // source col pre-XORed so LDS[r][chunk c] = A[r][c ^ (r&7)].
    const int srow  = w * 32 + (lane >> 3);
    const int sxor  = (lane >> 3) & 7;            // == srow & 7 (w*32, i*8 ≡ 0 mod 8)
    const int scol  = (lane & 7) * 8;             // LDS dest col (linear)
    const int sgcol = ((lane & 7) ^ sxor) * 8;    // swizzled global source col
    const __bf16* Aptr = Ablk + (long)srow * lda + sgcol;

    // B staging: global fp32 (unswizzled) -> regs -> cvt -> swizzled ds_write.
    const int br0  = tid >> 3;                    // rows br0 + i*32
    const int bxor = br0 & 7;                     // (br0 + 32i) & 7 invariant
    const int bgc  = (tid & 7) * 8;               // global col
    const int bwc  = ((tid & 7) ^ bxor) * 8;      // swizzled LDS write col
    const float* Bptr = Bblk + (long)br0 * ldb + bgc;

    const int rx = n16 & 7;                       // read-side row XOR (lane-const)

    float4 breg[4][2];

#define STAGE_A(bi, kk)                                                        \
    _Pragma("unroll") for (int i = 0; i < 4; i++)                              \
        load_lds16(Aptr + (long)i * 8 * lda + (kk), &As[bi][srow + i * 8][scol]);

#define LOAD_B(kk)                                                             \
    _Pragma("unroll") for (int i = 0; i < 4; i++) {                            \
        breg[i][0] = *(const float4*)(Bptr + (long)i * 32 * ldb + (kk));       \
        breg[i][1] = *(const float4*)(Bptr + (long)i * 32 * ldb + (kk) + 4);   \
    }

#define WRITE_B(bi)                                                            \
    _Pragma("unroll") for (int i = 0; i < 4; i++) {                            \
        bf16x8 bb;                                                             \
        bb[0] = (__bf16)breg[i][0].x; bb[1] = (__bf16)breg[i][0].y;            \
        bb[2] = (__bf16)breg[i][0].z; bb[3] = (__bf16)breg[i][0].w;            \
        bb[4] = (__bf16)breg[i][1].x; bb[5] = (__bf16)breg[i][1].y;            \
        bb[6] = (__bf16)breg[i][1].z; bb[7] = (__bf16)breg[i][1].w;            \
        *(bf16x8*)&Bs[bi][br0 + i * 32][bwc] = bb;                             \
    }

    // prologue: tile 0
    STAGE_A(0, 0);
    LOAD_B(0);
    WRITE_B(0);
    __syncthreads();   // compiler drains vmcnt(0) here (gload_lds landed)

    int buf = 0;
    for (int k0 = 0;; k0 += 64) {
        const bool last = (k0 + 64 >= K);
        if (!last) {
            STAGE_A(buf ^ 1, k0 + 64);   // async DMA in flight across compute
            LOAD_B(k0 + 64);             // global->reg in flight across compute
        }
#pragma unroll
        for (int ks = 0; ks < 2; ks++) {
            bf16x8 af[4], bfr[4];
#pragma unroll
            for (int i = 0; i < 4; i++)
                af[i] = *(const bf16x8*)
                    &As[buf][wm + i * 16 + n16][((ks * 4 + quad) ^ rx) * 8];
#pragma unroll
            for (int j = 0; j < 4; j++)
                bfr[j] = *(const bf16x8*)
                    &Bs[buf][wn + j * 16 + n16][((ks * 4 + quad) ^ rx) * 8];
#pragma unroll
            for (int i = 0; i < 4; i++)
#pragma unroll
                for (int j = 0; j < 4; j++)
                    acc[i][j] = MFMA16(af[i], bfr[j], acc[i][j]);
        }
        if (last) break;
        WRITE_B(buf ^ 1);    // reg-dep waitcnt on breg only; other buffer, no race
        __syncthreads();     // one barrier per K-step
        buf ^= 1;
    }

#undef STAGE_A
#undef LOAD_B
#undef WRITE_B

#pragma unroll
    for (int i = 0; i < 4; i++)
#pragma unroll
        for (int j = 0; j < 4; j++)
#pragma unroll
            for (int r = 0; r < 4; r++)
                Cblk[(long)(wm + i * 16 + quad * 4 + r) * ldc + wn + j * 16 + n16] =
                    (OutT)acc[i][j][r];
}

// ---------------------------------------------------------------------------
// Fused k + v + q projections in ONE launch (640 blocks).
// blocks 0..191: k, 192..383: v, 384..639: q.
// ---------------------------------------------------------------------------
__global__ __launch_bounds__(256) void gemm_kvq(const __bf16* __restrict__ tgtb,
                                                const __bf16* __restrict__ hidb,
                                                const float* __restrict__ wk,
                                                const float* __restrict__ wv,
                                                const float* __restrict__ wq,
                                                __bf16* __restrict__ kbf,
                                                __bf16* __restrict__ vbf,
                                                __bf16* __restrict__ qbf) {
    const int b = blockIdx.x;
    const __bf16* Ap; const float* Bp; __bf16* Cp; int ldc;
    if (b < 384) {
        const int z = b / 192, bb = b - z * 192;
        const int n0 = (bb & 7) * 128, m0 = (bb >> 3) * 128;
        Ap = (m0 < 2048) ? tgtb + (long)m0 * 2048 : hidb + (long)(m0 - 2048) * 2048;
        Bp = (z ? wv : wk) + (long)n0 * 2048;
        Cp = (z ? vbf : kbf) + (long)m0 * 1024 + n0;
        ldc = 1024;
    } else {
        const int bb = b - 384;
        const int n0 = (bb & 31) * 128, m0 = (bb >> 5) * 128;
        Ap = hidb + (long)m0 * 2048;
        Bp = wq + (long)n0 * 2048;
        Cp = qbf + (long)m0 * 4096 + n0;
        ldc = 4096;
    }
    gemm128_f32b<__bf16>(Ap, Bp, Cp, 2048, 2048, 2048, ldc);
}

// ---------------------------------------------------------------------------
// Output projection, split-K=4 (512 blocks), fp32 partials.
// ---------------------------------------------------------------------------
__global__ __launch_bounds__(256) void gemm_wo_splitk(const __bf16* __restrict__ A,
                                                      const float* __restrict__ B,
                                                      float* __restrict__ po) {
    const int m0 = blockIdx.y * 128;
    const int n0 = blockIdx.x * 128;
    const int koff = blockIdx.z * 1024;
    float* C = po + (long)blockIdx.z * 1024 * 2048;
    gemm128_f32b<float>(A + (long)m0 * 4096 + koff, B + (long)n0 * 4096 + koff,
                        C + (long)m0 * 2048 + n0, 1024, 4096, 4096, 2048);
}

__global__ __launch_bounds__(256) void add4(const float* __restrict__ po,
                                            float* __restrict__ out, int n4) {
    int i = blockIdx.x * 256 + threadIdx.x;
    int stride = gridDim.x * 256;
    const long seg = (long)1024 * 2048 / 4;
    for (; i < n4; i += stride) {
        float4 a = ((const float4*)po)[i];
        float4 b = ((const float4*)po)[i + seg];
        float4 c = ((const float4*)po)[i + 2 * seg];
        float4 d = ((const float4*)po)[i + 3 * seg];
        float4 o;
        o.x = (a.x + b.x) + (c.x + d.x);
        o.y = (a.y + b.y) + (c.y + d.y);
        o.z = (a.z + b.z) + (c.z + d.z);
        o.w = (a.w + b.w) + (c.w + d.w);
        ((float4*)out)[i] = o;
    }
}

// ---------------------------------------------------------------------------
// Fused RMSNorm+RoPE for q (z=0) and k (z=1), in place.
// ---------------------------------------------------------------------------
__global__ __launch_bounds__(256) void rmsnorm_rope2(__bf16* __restrict__ xq,
                                                     const float* __restrict__ wq,
                                                     __bf16* __restrict__ xk,
                                                     const float* __restrict__ wk,
                                                     const float* __restrict__ cosb,
                                                     const float* __restrict__ sinb) {
    const int z = blockIdx.y;
    __bf16*      x = z ? xk : xq;
    const float* w = z ? wk : wq;
    const int nheads     = z ? 8 : 32;
    const int row_stride = z ? 1024 : 4096;
    const int pos_offset = z ? 0 : 2048;
    const float outscale = z ? 1.0f : 0.08838834764831845f;
    const int nitems     = z ? 3072 * 8 : 1024 * 32;

    int item = blockIdx.x * 4 + (threadIdx.x >> 6);
    int lane = threadIdx.x & 63;
    if (item >= nitems) return;
    int row = item / nheads;
    int head = item - row * nheads;
    __bf16* p = x + (long)row * row_stride + head * HD;

    float x1 = (float)p[lane], x2 = (float)p[lane + 64];
    float ss = x1 * x1 + x2 * x2;
#pragma unroll
    for (int o = 32; o >= 1; o >>= 1) ss += __shfl_xor(ss, o);
    float r = rsqrtf(ss * (1.0f / 128.0f) + 1e-6f) * outscale;

    int pos = pos_offset + row;
    float c1 = cosb[pos * HD + lane], c2 = cosb[pos * HD + lane + 64];
    float s1 = sinb[pos * HD + lane], s2 = sinb[pos * HD + lane + 64];
    float y1 = x1 * r * w[lane];
    float y2 = x2 * r * w[lane + 64];
    p[lane]      = (__bf16)(y1 * c1 - y2 * s1);
    p[lane + 64] = (__bf16)(y2 * c2 + y1 * s2);
}

// ---------------------------------------------------------------------------
// V transpose: vbf[t][g*128+d] -> vt[g][d][t]
// ---------------------------------------------------------------------------
__global__ __launch_bounds__(256) void transpose_v(const __bf16* __restrict__ v,
                                                   __bf16* __restrict__ vt) {
    __shared__ __bf16 T[64][68];
    const int tid = threadIdx.x;
    const int t0 = blockIdx.x * 64;
    const int d0 = blockIdx.y * 64;
    const int g  = blockIdx.z;
    const __bf16* src = v + (long)t0 * 1024 + g * 128 + d0;
#pragma unroll
    for (int i = 0; i < 4; i++) {
        int idx = tid + i * 256;
        int r = idx >> 4, c4 = (idx & 15) * 4;
        *(bf16x4*)&T[r][c4] = *(const bf16x4*)(src + (long)r * 1024 + c4);
    }
    __syncthreads();
    __bf16* dst = vt + (long)g * 128 * 3072 + (long)d0 * 3072 + t0;
#pragma unroll
    for (int i = 0; i < 4; i++) {
        int idx = tid + i * 256;
        int r = idx >> 4, c4 = (idx & 15) * 4;
        bf16x4 o;
        o[0] = T[c4 + 0][r]; o[1] = T[c4 + 1][r];
        o[2] = T[c4 + 2][r]; o[3] = T[c4 + 3][r];
        *(bf16x4*)(dst + (long)r * 3072 + c4) = o;
    }
}

// ---------------------------------------------------------------------------
// Split-K flash attention, 128 q-rows per block (4 waves x 2 m-tiles of 16).
// S computed TRANSPOSED (S^T = K Q^T, pure operand swap: A/B fragment lane
// layouts are identical for 16x16x32) so P exits with t in the register
// direction -> P->LDS is 8 packed ds_write_b64 per wave-tile instead of 32
// scalar b16 writes, and the row-sum is lane-local. PV phase, O layout,
// epilogue and merge are unchanged. Ps aliases Ks (stride 68).
// ---------------------------------------------------------------------------
__global__ __launch_bounds__(256) void flash_attn_splitk(const __bf16* __restrict__ qb,
                                                         const __bf16* __restrict__ kb,
                                                         const __bf16* __restrict__ vtg,
                                                         __bf16* __restrict__ Opart0,
                                                         __bf16* __restrict__ Opart1,
                                                         float* __restrict__ lsum) {
    __shared__ __bf16 KsU[64 * 136];   // Ks[t][d] stride 136; Ps aliased (4*32*68 = 8704)
    __shared__ __bf16 Vs[128][72];     // [d][t]
#define KS(r, c) KsU[(r) * 136 + (c)]
#define PS(w_, m_, t_) KsU[(w_) * 2176 + (m_) * 68 + (t_)]

    const int tid  = threadIdx.x;
    const int lane = tid & 63;
    const int w    = tid >> 6;
    const int n    = lane & 15;
    const int quad = lane >> 4;

    const int bid = blockIdx.x;        // 0..255
    const int s   = blockIdx.y;
    const int g  = bid & 7;
    const int jj = bid >> 3;           // 0..31
    const int h  = g * 4 + (jj & 3);
    const int qt = jj >> 2;            // 0..7, 128-row q tiles

    const int qr0 = qt * 128 + w * 16; // m-tile 0 base; m-tile 1 = +64

    bf16x8 qf[2][4];
#pragma unroll
    for (int mt = 0; mt < 2; mt++) {
        const __bf16* qp = qb + (long)(qr0 + mt * 64 + n) * 4096 + h * 128 + quad * 8;
        qf[mt][0] = *(const bf16x8*)(qp);
        qf[mt][1] = *(const bf16x8*)(qp + 32);
        qf[mt][2] = *(const bf16x8*)(qp + 64);
        qf[mt][3] = *(const bf16x8*)(qp + 96);
    }

    f32x4 O[2][8];
    const f32x4 fzero = {0.f, 0.f, 0.f, 0.f};
#pragma unroll
    for (int mt = 0; mt < 2; mt++)
#pragma unroll
        for (int dt = 0; dt < 8; dt++) O[mt][dt] = fzero;
    float l_loc[2] = {0.f, 0.f};       // lane-local: lane n16 owns q-row qr0+mt*64+n

    const int ntot = 34 + 2 * qt;      // even
    const int half = ntot >> 1;
    const int tbeg = s ? half : 0;
    const int tend = s ? ntot : half;

    const int krr = tid >> 4, kc8 = (tid & 15) * 8;
    const int vrr = tid >> 3, vc8 = (tid & 7) * 8;
    const __bf16* kp = kb + g * 128 + (long)(tbeg * 64 + krr) * 1024 + kc8;
    const __bf16* vp = vtg + (long)g * 128 * 3072 + (long)vrr * 3072 + tbeg * 64 + vc8;

    for (int tt = tbeg; tt < tend; tt++) {
#pragma unroll
        for (int i = 0; i < 4; i++)
            *(bf16x8*)&KS(krr + i * 16, kc8) = *(const bf16x8*)(kp + (long)i * 16 * 1024);
#pragma unroll
        for (int i = 0; i < 4; i++)
            *(bf16x8*)&Vs[vrr + i * 32][vc8] = *(const bf16x8*)(vp + (long)i * 32 * 3072);
        kp += 64 * 1024;
        vp += 64;
        __syncthreads();

        // S^T = K Q^T: A = K-frag, B = Q-frag (identical lane layouts).
        // Result: col(lane&15) = q-row, row(quad*4+r) = key t.
        f32x4 S[2][4];
#pragma unroll
        for (int nt = 0; nt < 4; nt++) {
            f32x4 a0 = fzero, a1 = fzero;
#pragma unroll
            for (int ks = 0; ks < 4; ks++) {
                bf16x8 kf = *(const bf16x8*)&KS(nt * 16 + n, ks * 32 + quad * 8);
                a0 = MFMA16(kf, qf[0][ks], a0);
                a1 = MFMA16(kf, qf[1][ks], a1);
            }
            S[0][nt] = a0;
            S[1][nt] = a1;
        }

        if (tt >= ntot - 2) {   // diagonal band spans the last two tiles
            const int t0 = tt * 64;
#pragma unroll
            for (int mt = 0; mt < 2; mt++) {
                const int lim = 2048 + qr0 + mt * 64 + n;   // q-row = lane index
#pragma unroll
                for (int nt = 0; nt < 4; nt++)
#pragma unroll
                    for (int r = 0; r < 4; r++) {
                        int t = t0 + nt * 16 + quad * 4 + r;
                        if (t > lim) S[mt][nt][r] = -1e30f;
                    }
            }
        }

        __syncthreads();   // all Ks reads done; Ps may overwrite

        // fixed-shift softmax; row-sum is lane-local (lane owns its q-row)
#pragma unroll
        for (int mt = 0; mt < 2; mt++)
#pragma unroll
            for (int nt = 0; nt < 4; nt++)
#pragma unroll
                for (int r = 0; r < 4; r++) {
                    float p = __expf(S[mt][nt][r] - MSTATIC);
                    S[mt][nt][r] = p;
                    l_loc[mt] += p;
                }

        // P -> LDS: packed b64 writes (4 consecutive t per (mt,nt))
#pragma unroll
        for (int mt = 0; mt < 2; mt++)
#pragma unroll
            for (int nt = 0; nt < 4; nt++) {
                bf16x4 pk;
#pragma unroll
                for (int r = 0; r < 4; r++) pk[r] = (__bf16)S[mt][nt][r];
                *(bf16x4*)&PS(w, mt * 16 + n, nt * 16 + quad * 4) = pk;
            }

        bf16x8 pa[2][2];
#pragma unroll
        for (int mt = 0; mt < 2; mt++)
#pragma unroll
            for (int kg = 0; kg < 2; kg++)
                pa[mt][kg] = *(const bf16x8*)&PS(w, mt * 16 + n, kg * 32 + quad * 8);

#pragma unroll
        for (int dt = 0; dt < 8; dt++) {
            bf16x8 vf0 = *(const bf16x8*)&Vs[dt * 16 + n][quad * 8];
            bf16x8 vf1 = *(const bf16x8*)&Vs[dt * 16 + n][32 + quad * 8];
#pragma unroll
            for (int mt = 0; mt < 2; mt++) {
                f32x4 acc = O[mt][dt];
                acc = MFMA16(pa[mt][0], vf0, acc);
                acc = MFMA16(pa[mt][1], vf1, acc);
                O[mt][dt] = acc;
            }
        }
        __syncthreads();
    }

    // row-sum: reduce across the 4 quads (lane already holds its row's partial)
#pragma unroll
    for (int mt = 0; mt < 2; mt++) {
        float sm = l_loc[mt];
        sm += __shfl_xor(sm, 16);
        sm += __shfl_xor(sm, 32);
        l_loc[mt] = sm;
    }

    __bf16* Op = s ? Opart1 : Opart0;
    const long tb = (long)(h * 8 + qt) * 128 * 128;
#pragma unroll
    for (int mt = 0; mt < 2; mt++)
#pragma unroll
        for (int dt = 0; dt < 8; dt++)
#pragma unroll
            for (int r = 0; r < 4; r++)
                Op[tb + (long)(mt * 64 + w * 16 + quad * 4 + r) * 128 + dt * 16 + n] =
                    (__bf16)O[mt][dt][r];
    if (quad == 0) {
        const int lb = (s * 256 + h * 8 + qt) * 128 + w * 16;
#pragma unroll
        for (int mt = 0; mt < 2; mt++)
            lsum[lb + mt * 64 + n] = l_loc[mt];
    }
#undef KS
#undef PS
}

// ---------------------------------------------------------------------------
// Additive merge of split-K partials -> normalized bf16 O over qbf.
// ---------------------------------------------------------------------------
__global__ __launch_bounds__(256) void flash_merge(const __bf16* __restrict__ O0,
                                                   const __bf16* __restrict__ O1,
                                                   const float* __restrict__ lsum,
                                                   __bf16* __restrict__ ob) {
    const int bx = blockIdx.x;         // 512: (h, qt, half64)
    const int h   = bx >> 4;
    const int r6  = bx & 15;
    const int qt  = r6 >> 1;
    const int sub = r6 & 1;
    const int row  = threadIdx.x >> 2;
    const int cseg = (threadIdx.x & 3) * 32;
    const int mrow = sub * 64 + row;

    const int tilei = h * 8 + qt;
    float inv = 1.0f / (lsum[tilei * 128 + mrow] + lsum[(256 + tilei) * 128 + mrow]);

    const long src = (long)tilei * 128 * 128 + (long)mrow * 128 + cseg;
    __bf16* dst = ob + (long)(qt * 128 + mrow) * 4096 + h * 128 + cseg;
#pragma unroll
    for (int j = 0; j < 4; j++) {
        bf16x8 x0 = *(const bf16x8*)(O0 + src + j * 8);
        bf16x8 x1 = *(const bf16x8*)(O1 + src + j * 8);
        bf16x8 o;
#pragma unroll
        for (int k = 0; k < 8; k++)
            o[k] = (__bf16)(((float)x0[k] + (float)x1[k]) * inv);
        *(bf16x8*)(dst + j * 8) = o;
    }
}

// ---------------------------------------------------------------------------
extern "C" void kernel_launch(void* const* d_in, const int* in_sizes, int n_in,
                              void* d_out, int out_size, void* d_ws, size_t ws_size,
                              hipStream_t stream) {
    const float* hidden = (const float*)d_in[0];
    const float* target = (const float*)d_in[1];
    const float* cosb   = (const float*)d_in[2];
    const float* sinb   = (const float*)d_in[3];
    const float* wq = (const float*)d_in[5];
    const float* wk = (const float*)d_in[6];
    const float* wv = (const float*)d_in[7];
    const float* wo = (const float*)d_in[8];
    const float* qw = (const float*)d_in[9];
    const float* kw = (const float*)d_in[10];
    float* out = (float*)d_out;

    // 40 MB workspace, phased overlays (launch order guarantees safety):
    char* ws = (char*)d_ws;
    const long MB = 1 << 20;
    __bf16* qbf  = (__bf16*)(ws);             // @0..8    q / attn out (live throughout)
    __bf16* kbf  = (__bf16*)(ws + 8 * MB);    // @8..14   k (dead after flash)
    __bf16* vbf  = (__bf16*)(ws + 14 * MB);   // @14..20  v (dead after transpose)
    __bf16* hidb = (__bf16*)(ws + 20 * MB);   // @20..24  (dead after gemm_kvq)
    __bf16* tgtb = (__bf16*)(ws + 24 * MB);   // @24..32  (dead after gemm_kvq)
    __bf16* vtg  = (__bf16*)(ws + 24 * MB);   // @24..30  (post-kvq)
    __bf16* Op1  = (__bf16*)(ws + 14 * MB);   // @14..22  (post-transpose)
    float*  lbuf = (float*)(ws + 22 * MB);    // @22..22.25
    __bf16* Op0  = (__bf16*)(ws + 30 * MB);   // @30..38
    float*  po   = (float*)(ws + 8 * MB);     // @8..40   wo partials (post-merge)

    dim3 blk(256);

    // activations -> bf16
    conv2_f32_bf16<<<dim3(1024, 2), blk, 0, stream>>>(
        target, tgtb, (2048 * 2048) / 4, hidden, hidb, (1024 * 2048) / 4);

    // all three projections, one launch (weights fp32, converted in-GEMM)
    gemm_kvq<<<640, blk, 0, stream>>>(tgtb, hidb, wk, wv, wq, kbf, vbf, qbf);

    // fused RMSNorm + RoPE (q and k)
    rmsnorm_rope2<<<dim3(8192, 2), blk, 0, stream>>>(qbf, qw, kbf, kw, cosb, sinb);

    // V transpose -> [g][d][t]
    transpose_v<<<dim3(48, 2, 8), blk, 0, stream>>>(vbf, vtg);

    // split-K flash attention (512 blocks, 128 q-rows each) + additive merge
    flash_attn_splitk<<<dim3(256, 2), blk, 0, stream>>>(qbf, kbf, vtg, Op0, Op1, lbuf);
    flash_merge<<<512, blk, 0, stream>>>(Op0, Op1, lbuf, qbf);

    // output projection: split-K=4 (512 blocks) + reduce
    gemm_wo_splitk<<<dim3(16, 8, 4), blk, 0, stream>>>(qbf, wo, po);
    add4<<<1024, blk, 0, stream>>>(po, out, (1024 * 2048) / 4);
}

// Round 2
// 359.966 us; speedup vs baseline: 1.0917x; 1.0447x over previous
//
#include <hip/hip_runtime.h>

#define HIDDEN 2048
#define NQ     1024
#define NCTX   2048
#define NTOT   3072
#define NHEADS 32
#define KVH    8
#define HD     128

typedef __attribute__((ext_vector_type(8))) __bf16 bf16x8;
typedef __attribute__((ext_vector_type(4))) __bf16 bf16x4;
typedef __attribute__((ext_vector_type(4))) float  f32x4;

#define MFMA16(a, b, c) __builtin_amdgcn_mfma_f32_16x16x32_bf16(a, b, c, 0, 0, 0)

// Fixed softmax shift (Cauchy-Schwarz: |q|=1 after folded 1/sqrt(d), |k|=sqrt(128),
// RoPE norm-preserving => s <= 11.4 incl. bf16 rounding).
#define MSTATIC 12.0f

__device__ __forceinline__ void load_lds16(const void* g, void* l) {
    __builtin_amdgcn_global_load_lds(
        (const __attribute__((address_space(1))) unsigned int*)g,
        (__attribute__((address_space(3))) unsigned int*)l, 16, 0, 0);
}

// ---------------------------------------------------------------------------
// 4-way fused fp32 -> bf16 convert (activations + k/v weights)
// ---------------------------------------------------------------------------
__global__ __launch_bounds__(256) void conv4_f32_bf16(const float* __restrict__ s0,
                                                      __bf16* __restrict__ d0, int n0,
                                                      const float* __restrict__ s1,
                                                      __bf16* __restrict__ d1, int n1,
                                                      const float* __restrict__ s2,
                                                      __bf16* __restrict__ d2, int n2,
                                                      const float* __restrict__ s3,
                                                      __bf16* __restrict__ d3, int n3) {
    const float* s; __bf16* d; int n;
    switch (blockIdx.y) {
        case 0:  s = s0; d = d0; n = n0; break;
        case 1:  s = s1; d = d1; n = n1; break;
        case 2:  s = s2; d = d2; n = n2; break;
        default: s = s3; d = d3; n = n3; break;
    }
    int i = blockIdx.x * 256 + threadIdx.x;
    int stride = gridDim.x * 256;
    for (; i < n; i += stride) {
        float4 v = ((const float4*)s)[i];
        bf16x4 o;
        o[0] = (__bf16)v.x; o[1] = (__bf16)v.y;
        o[2] = (__bf16)v.z; o[3] = (__bf16)v.w;
        ((bf16x4*)d)[i] = o;
    }
}

// wo (2048 x 4096) fp32 -> two bf16 K-halves (ld 2048), matching split-K blocks.
__global__ __launch_bounds__(256) void conv_wo(const float* __restrict__ wo,
                                               __bf16* __restrict__ w0,
                                               __bf16* __restrict__ w1) {
    int i = blockIdx.x * 256 + threadIdx.x;
    int stride = gridDim.x * 256;
    for (; i < 2048 * 1024; i += stride) {   // 1024 float4 per row
        int r = i >> 10, cc = i & 1023;
        float4 v = ((const float4*)wo)[i];
        bf16x4 o;
        o[0] = (__bf16)v.x; o[1] = (__bf16)v.y;
        o[2] = (__bf16)v.z; o[3] = (__bf16)v.w;
        __bf16* dst = (cc & 512) ? w1 : w0;
        *(bf16x4*)(dst + (long)r * 2048 + (cc & 511) * 4) = o;
    }
}

// ---------------------------------------------------------------------------
// 128x128 MFMA GEMM tile bodies, m97-style single-buffer (32 KB LDS -> 4-5
// blocks/CU, whole 640-block grid resident => no scheduling tail, which the
// R8 counters showed costs ~37%: Occupancy 15% == 2-blocks/CU dbuf + tail).
// XOR bank-swizzle retained (R8-verified, conflicts 1.57e7 -> 0): linear LDS
// dest (gload_lds requirement) + pre-swizzled global source + swizzled read.
//   bb: both operands bf16, pure async global->LDS staging (zero VALU).
//   fb: A bf16 async; B fp32 reg-staged, LOAD one K-step ahead so the HBM
//       latency hides under the previous compute phase (T14 issue-early).
// ---------------------------------------------------------------------------
__device__ __forceinline__ void gemm_compute64(const __bf16 (&As)[128][64],
                                               const __bf16 (&Bs)[128][64],
                                               f32x4 (&acc)[4][4],
                                               int wm, int wn, int n16, int quad, int rx) {
#pragma unroll
    for (int ks = 0; ks < 2; ks++) {
        bf16x8 af[4], bfr[4];
#pragma unroll
        for (int i = 0; i < 4; i++)
            af[i] = *(const bf16x8*)&As[wm + i * 16 + n16][((ks * 4 + quad) ^ rx) * 8];
#pragma unroll
        for (int j = 0; j < 4; j++)
            bfr[j] = *(const bf16x8*)&Bs[wn + j * 16 + n16][((ks * 4 + quad) ^ rx) * 8];
#pragma unroll
        for (int i = 0; i < 4; i++)
#pragma unroll
            for (int j = 0; j < 4; j++)
                acc[i][j] = MFMA16(af[i], bfr[j], acc[i][j]);
    }
}

template <typename OutT>
__device__ __forceinline__ void gemm_epilogue(const f32x4 (&acc)[4][4],
                                              OutT* __restrict__ Cblk, int ldc,
                                              int wm, int wn, int n16, int quad) {
#pragma unroll
    for (int i = 0; i < 4; i++)
#pragma unroll
        for (int j = 0; j < 4; j++)
#pragma unroll
            for (int r = 0; r < 4; r++)
                Cblk[(long)(wm + i * 16 + quad * 4 + r) * ldc + wn + j * 16 + n16] =
                    (OutT)acc[i][j][r];
}

template <typename OutT>
__device__ __forceinline__ void gemm128_bb(__bf16 (&As)[128][64], __bf16 (&Bs)[128][64],
                                           const __bf16* __restrict__ Ablk,
                                           const __bf16* __restrict__ Bblk,
                                           OutT* __restrict__ Cblk,
                                           int K, int lda, int ldb, int ldc) {
    const int tid  = threadIdx.x;
    const int lane = tid & 63;
    const int w    = tid >> 6;
    const int n16  = lane & 15;
    const int quad = lane >> 4;
    const int wm = (w & 1) * 64;
    const int wn = (w >> 1) * 64;

    f32x4 acc[4][4];
    const f32x4 fzero = {0.f, 0.f, 0.f, 0.f};
#pragma unroll
    for (int i = 0; i < 4; i++)
#pragma unroll
        for (int j = 0; j < 4; j++) acc[i][j] = fzero;

    const int srow  = w * 32 + (lane >> 3);
    const int sxor  = (lane >> 3) & 7;
    const int scol  = (lane & 7) * 8;             // linear LDS dest col
    const int sgcol = ((lane & 7) ^ sxor) * 8;    // pre-swizzled global col
    const __bf16* Ap = Ablk + (long)srow * lda + sgcol;
    const __bf16* Bp = Bblk + (long)srow * ldb + sgcol;
    const int rx = n16 & 7;

    for (int k0 = 0; k0 < K; k0 += 64) {
#pragma unroll
        for (int i = 0; i < 4; i++) {
            load_lds16(Ap + (long)i * 8 * lda + k0, &As[srow + i * 8][scol]);
            load_lds16(Bp + (long)i * 8 * ldb + k0, &Bs[srow + i * 8][scol]);
        }
        __syncthreads();
        gemm_compute64(As, Bs, acc, wm, wn, n16, quad, rx);
        __syncthreads();
    }
    gemm_epilogue(acc, Cblk, ldc, wm, wn, n16, quad);
}

template <typename OutT>
__device__ __forceinline__ void gemm128_fb(__bf16 (&As)[128][64], __bf16 (&Bs)[128][64],
                                           const __bf16* __restrict__ Ablk,
                                           const float* __restrict__ Bblk,
                                           OutT* __restrict__ Cblk,
                                           int K, int lda, int ldb, int ldc) {
    const int tid  = threadIdx.x;
    const int lane = tid & 63;
    const int w    = tid >> 6;
    const int n16  = lane & 15;
    const int quad = lane >> 4;
    const int wm = (w & 1) * 64;
    const int wn = (w >> 1) * 64;

    f32x4 acc[4][4];
    const f32x4 fzero = {0.f, 0.f, 0.f, 0.f};
#pragma unroll
    for (int i = 0; i < 4; i++)
#pragma unroll
        for (int j = 0; j < 4; j++) acc[i][j] = fzero;

    const int srow  = w * 32 + (lane >> 3);
    const int sxor  = (lane >> 3) & 7;
    const int scol  = (lane & 7) * 8;
    const int sgcol = ((lane & 7) ^ sxor) * 8;
    const __bf16* Ap = Ablk + (long)srow * lda + sgcol;

    const int br0  = tid >> 3;
    const int bxor = br0 & 7;
    const int bgc  = (tid & 7) * 8;
    const int bwc  = ((tid & 7) ^ bxor) * 8;
    const float* Bptr = Bblk + (long)br0 * ldb + bgc;

    const int rx = n16 & 7;
    float4 breg[4][2];

#define LOAD_B(kk)                                                             \
    _Pragma("unroll") for (int i = 0; i < 4; i++) {                            \
        breg[i][0] = *(const float4*)(Bptr + (long)i * 32 * ldb + (kk));       \
        breg[i][1] = *(const float4*)(Bptr + (long)i * 32 * ldb + (kk) + 4);   \
    }

    LOAD_B(0);
    for (int k0 = 0; k0 < K; k0 += 64) {
#pragma unroll
        for (int i = 0; i < 4; i++)
            load_lds16(Ap + (long)i * 8 * lda + k0, &As[srow + i * 8][scol]);
#pragma unroll
        for (int i = 0; i < 4; i++) {
            bf16x8 bb;
            bb[0] = (__bf16)breg[i][0].x; bb[1] = (__bf16)breg[i][0].y;
            bb[2] = (__bf16)breg[i][0].z; bb[3] = (__bf16)breg[i][0].w;
            bb[4] = (__bf16)breg[i][1].x; bb[5] = (__bf16)breg[i][1].y;
            bb[6] = (__bf16)breg[i][1].z; bb[7] = (__bf16)breg[i][1].w;
            *(bf16x8*)&Bs[br0 + i * 32][bwc] = bb;
        }
        if (k0 + 64 < K) LOAD_B(k0 + 64);   // in flight across compute below
        __syncthreads();
        gemm_compute64(As, Bs, acc, wm, wn, n16, quad, rx);
        __syncthreads();
    }
#undef LOAD_B
    gemm_epilogue(acc, Cblk, ldc, wm, wn, n16, quad);
}

// ---------------------------------------------------------------------------
// Fused k + v + q projections in ONE launch (640 blocks, all resident).
// blocks 0..191: k (bf16 weights), 192..383: v (bf16), 384..639: q (fp32 wq).
// ---------------------------------------------------------------------------
__global__ __launch_bounds__(256) void gemm_kvq(const __bf16* __restrict__ tgtb,
                                                const __bf16* __restrict__ hidb,
                                                const __bf16* __restrict__ wkb,
                                                const __bf16* __restrict__ wvb,
                                                const float* __restrict__ wq,
                                                __bf16* __restrict__ kbf,
                                                __bf16* __restrict__ vbf,
                                                __bf16* __restrict__ qbf) {
    __shared__ __bf16 As[128][64];
    __shared__ __bf16 Bs[128][64];
    const int b = blockIdx.x;
    if (b < 384) {
        const int z = b / 192, bb = b - z * 192;
        const int n0 = (bb & 7) * 128, m0 = (bb >> 3) * 128;
        const __bf16* Ap = (m0 < 2048) ? tgtb + (long)m0 * 2048
                                       : hidb + (long)(m0 - 2048) * 2048;
        const __bf16* Bp = (z ? wvb : wkb) + (long)n0 * 2048;
        __bf16* Cp = (z ? vbf : kbf) + (long)m0 * 1024 + n0;
        gemm128_bb<__bf16>(As, Bs, Ap, Bp, Cp, 2048, 2048, 2048, 1024);
    } else {
        const int bb = b - 384;
        const int n0 = (bb & 31) * 128, m0 = (bb >> 5) * 128;
        gemm128_fb<__bf16>(As, Bs, hidb + (long)m0 * 2048, wq + (long)n0 * 2048,
                           qbf + (long)m0 * 4096 + n0, 2048, 2048, 2048, 4096);
    }
}

// ---------------------------------------------------------------------------
// Output projection, split-K=2 over the pre-split bf16 wo halves.
// z=0 partial goes straight to the fp32 out buffer; z=1 to po1; add2 sums.
// ---------------------------------------------------------------------------
__global__ __launch_bounds__(256) void gemm_wo2(const __bf16* __restrict__ A,
                                                const __bf16* __restrict__ w0,
                                                const __bf16* __restrict__ w1,
                                                float* __restrict__ out,
                                                float* __restrict__ po1) {
    __shared__ __bf16 As[128][64];
    __shared__ __bf16 Bs[128][64];
    const int m0 = blockIdx.y * 128;
    const int n0 = blockIdx.x * 128;
    const int z  = blockIdx.z;
    const __bf16* Bp = (z ? w1 : w0) + (long)n0 * 2048;
    float* C = (z ? po1 : out) + (long)m0 * 2048 + n0;
    gemm128_bb<float>(As, Bs, A + (long)m0 * 4096 + z * 2048, Bp, C,
                      2048, 4096, 2048, 2048);
}

__global__ __launch_bounds__(256) void add2_inplace(float* __restrict__ out,
                                                    const float* __restrict__ p1, int n4) {
    int i = blockIdx.x * 256 + threadIdx.x;
    int stride = gridDim.x * 256;
    for (; i < n4; i += stride) {
        float4 a = ((const float4*)out)[i];
        float4 b = ((const float4*)p1)[i];
        float4 o;
        o.x = a.x + b.x; o.y = a.y + b.y;
        o.z = a.z + b.z; o.w = a.w + b.w;
        ((float4*)out)[i] = o;
    }
}

// ---------------------------------------------------------------------------
// Fused RMSNorm+RoPE for q (z=0) and k (z=1), in place.
// ---------------------------------------------------------------------------
__global__ __launch_bounds__(256) void rmsnorm_rope2(__bf16* __restrict__ xq,
                                                     const float* __restrict__ wq,
                                                     __bf16* __restrict__ xk,
                                                     const float* __restrict__ wk,
                                                     const float* __restrict__ cosb,
                                                     const float* __restrict__ sinb) {
    const int z = blockIdx.y;
    __bf16*      x = z ? xk : xq;
    const float* w = z ? wk : wq;
    const int nheads     = z ? 8 : 32;
    const int row_stride = z ? 1024 : 4096;
    const int pos_offset = z ? 0 : 2048;
    const float outscale = z ? 1.0f : 0.08838834764831845f;
    const int nitems     = z ? 3072 * 8 : 1024 * 32;

    int item = blockIdx.x * 4 + (threadIdx.x >> 6);
    int lane = threadIdx.x & 63;
    if (item >= nitems) return;
    int row = item / nheads;
    int head = item - row * nheads;
    __bf16* p = x + (long)row * row_stride + head * HD;

    float x1 = (float)p[lane], x2 = (float)p[lane + 64];
    float ss = x1 * x1 + x2 * x2;
#pragma unroll
    for (int o = 32; o >= 1; o >>= 1) ss += __shfl_xor(ss, o);
    float r = rsqrtf(ss * (1.0f / 128.0f) + 1e-6f) * outscale;

    int pos = pos_offset + row;
    float c1 = cosb[pos * HD + lane], c2 = cosb[pos * HD + lane + 64];
    float s1 = sinb[pos * HD + lane], s2 = sinb[pos * HD + lane + 64];
    float y1 = x1 * r * w[lane];
    float y2 = x2 * r * w[lane + 64];
    p[lane]      = (__bf16)(y1 * c1 - y2 * s1);
    p[lane + 64] = (__bf16)(y2 * c2 + y1 * s2);
}

// ---------------------------------------------------------------------------
// V transpose: vbf[t][g*128+d] -> vt[g][d][t]
// ---------------------------------------------------------------------------
__global__ __launch_bounds__(256) void transpose_v(const __bf16* __restrict__ v,
                                                   __bf16* __restrict__ vt) {
    __shared__ __bf16 T[64][68];
    const int tid = threadIdx.x;
    const int t0 = blockIdx.x * 64;
    const int d0 = blockIdx.y * 64;
    const int g  = blockIdx.z;
    const __bf16* src = v + (long)t0 * 1024 + g * 128 + d0;
#pragma unroll
    for (int i = 0; i < 4; i++) {
        int idx = tid + i * 256;
        int r = idx >> 4, c4 = (idx & 15) * 4;
        *(bf16x4*)&T[r][c4] = *(const bf16x4*)(src + (long)r * 1024 + c4);
    }
    __syncthreads();
    __bf16* dst = vt + (long)g * 128 * 3072 + (long)d0 * 3072 + t0;
#pragma unroll
    for (int i = 0; i < 4; i++) {
        int idx = tid + i * 256;
        int r = idx >> 4, c4 = (idx & 15) * 4;
        bf16x4 o;
        o[0] = T[c4 + 0][r]; o[1] = T[c4 + 1][r];
        o[2] = T[c4 + 2][r]; o[3] = T[c4 + 3][r];
        *(bf16x4*)(dst + (long)r * 3072 + c4) = o;
    }
}

// ---------------------------------------------------------------------------
// Split-K flash attention, 128 q-rows per block (4 waves x 2 m-tiles of 16).
// S computed TRANSPOSED (S^T = K Q^T, pure operand swap: A/B fragment lane
// layouts are identical for 16x16x32) so P exits with t in the register
// direction -> P->LDS is 8 packed ds_write_b64 per wave-tile instead of 32
// scalar b16 writes, and the row-sum is lane-local. PV phase, O layout,
// epilogue and merge are unchanged. Ps aliases Ks (stride 68).
// ---------------------------------------------------------------------------
__global__ __launch_bounds__(256) void flash_attn_splitk(const __bf16* __restrict__ qb,
                                                         const __bf16* __restrict__ kb,
                                                         const __bf16* __restrict__ vtg,
                                                         __bf16* __restrict__ Opart0,
                                                         __bf16* __restrict__ Opart1,
                                                         float* __restrict__ lsum) {
    __shared__ __bf16 KsU[64 * 136];   // Ks[t][d] stride 136; Ps aliased (4*32*68 = 8704)
    __shared__ __bf16 Vs[128][72];     // [d][t]
#define KS(r, c) KsU[(r) * 136 + (c)]
#define PS(w_, m_, t_) KsU[(w_) * 2176 + (m_) * 68 + (t_)]

    const int tid  = threadIdx.x;
    const int lane = tid & 63;
    const int w    = tid >> 6;
    const int n    = lane & 15;
    const int quad = lane >> 4;

    const int bid = blockIdx.x;        // 0..255
    const int s   = blockIdx.y;
    const int g  = bid & 7;
    const int jj = bid >> 3;           // 0..31
    const int h  = g * 4 + (jj & 3);
    const int qt = jj >> 2;            // 0..7, 128-row q tiles

    const int qr0 = qt * 128 + w * 16; // m-tile 0 base; m-tile 1 = +64

    bf16x8 qf[2][4];
#pragma unroll
    for (int mt = 0; mt < 2; mt++) {
        const __bf16* qp = qb + (long)(qr0 + mt * 64 + n) * 4096 + h * 128 + quad * 8;
        qf[mt][0] = *(const bf16x8*)(qp);
        qf[mt][1] = *(const bf16x8*)(qp + 32);
        qf[mt][2] = *(const bf16x8*)(qp + 64);
        qf[mt][3] = *(const bf16x8*)(qp + 96);
    }

    f32x4 O[2][8];
    const f32x4 fzero = {0.f, 0.f, 0.f, 0.f};
#pragma unroll
    for (int mt = 0; mt < 2; mt++)
#pragma unroll
        for (int dt = 0; dt < 8; dt++) O[mt][dt] = fzero;
    float l_loc[2] = {0.f, 0.f};       // lane-local: lane n16 owns q-row qr0+mt*64+n

    const int ntot = 34 + 2 * qt;      // even
    const int half = ntot >> 1;
    const int tbeg = s ? half : 0;
    const int tend = s ? ntot : half;

    const int krr = tid >> 4, kc8 = (tid & 15) * 8;
    const int vrr = tid >> 3, vc8 = (tid & 7) * 8;
    const __bf16* kp = kb + g * 128 + (long)(tbeg * 64 + krr) * 1024 + kc8;
    const __bf16* vp = vtg + (long)g * 128 * 3072 + (long)vrr * 3072 + tbeg * 64 + vc8;

    for (int tt = tbeg; tt < tend; tt++) {
#pragma unroll
        for (int i = 0; i < 4; i++)
            *(bf16x8*)&KS(krr + i * 16, kc8) = *(const bf16x8*)(kp + (long)i * 16 * 1024);
#pragma unroll
        for (int i = 0; i < 4; i++)
            *(bf16x8*)&Vs[vrr + i * 32][vc8] = *(const bf16x8*)(vp + (long)i * 32 * 3072);
        kp += 64 * 1024;
        vp += 64;
        __syncthreads();

        // S^T = K Q^T: A = K-frag, B = Q-frag (identical lane layouts).
        // Result: col(lane&15) = q-row, row(quad*4+r) = key t.
        f32x4 S[2][4];
#pragma unroll
        for (int nt = 0; nt < 4; nt++) {
            f32x4 a0 = fzero, a1 = fzero;
#pragma unroll
            for (int ks = 0; ks < 4; ks++) {
                bf16x8 kf = *(const bf16x8*)&KS(nt * 16 + n, ks * 32 + quad * 8);
                a0 = MFMA16(kf, qf[0][ks], a0);
                a1 = MFMA16(kf, qf[1][ks], a1);
            }
            S[0][nt] = a0;
            S[1][nt] = a1;
        }

        if (tt >= ntot - 2) {   // diagonal band spans the last two tiles
            const int t0 = tt * 64;
#pragma unroll
            for (int mt = 0; mt < 2; mt++) {
                const int lim = 2048 + qr0 + mt * 64 + n;   // q-row = lane index
#pragma unroll
                for (int nt = 0; nt < 4; nt++)
#pragma unroll
                    for (int r = 0; r < 4; r++) {
                        int t = t0 + nt * 16 + quad * 4 + r;
                        if (t > lim) S[mt][nt][r] = -1e30f;
                    }
            }
        }

        __syncthreads();   // all Ks reads done; Ps may overwrite

        // fixed-shift softmax; row-sum is lane-local (lane owns its q-row)
#pragma unroll
        for (int mt = 0; mt < 2; mt++)
#pragma unroll
            for (int nt = 0; nt < 4; nt++)
#pragma unroll
                for (int r = 0; r < 4; r++) {
                    float p = __expf(S[mt][nt][r] - MSTATIC);
                    S[mt][nt][r] = p;
                    l_loc[mt] += p;
                }

        // P -> LDS: packed b64 writes (4 consecutive t per (mt,nt))
#pragma unroll
        for (int mt = 0; mt < 2; mt++)
#pragma unroll
            for (int nt = 0; nt < 4; nt++) {
                bf16x4 pk;
#pragma unroll
                for (int r = 0; r < 4; r++) pk[r] = (__bf16)S[mt][nt][r];
                *(bf16x4*)&PS(w, mt * 16 + n, nt * 16 + quad * 4) = pk;
            }

        bf16x8 pa[2][2];
#pragma unroll
        for (int mt = 0; mt < 2; mt++)
#pragma unroll
            for (int kg = 0; kg < 2; kg++)
                pa[mt][kg] = *(const bf16x8*)&PS(w, mt * 16 + n, kg * 32 + quad * 8);

#pragma unroll
        for (int dt = 0; dt < 8; dt++) {
            bf16x8 vf0 = *(const bf16x8*)&Vs[dt * 16 + n][quad * 8];
            bf16x8 vf1 = *(const bf16x8*)&Vs[dt * 16 + n][32 + quad * 8];
#pragma unroll
            for (int mt = 0; mt < 2; mt++) {
                f32x4 acc = O[mt][dt];
                acc = MFMA16(pa[mt][0], vf0, acc);
                acc = MFMA16(pa[mt][1], vf1, acc);
                O[mt][dt] = acc;
            }
        }
        __syncthreads();
    }

    // row-sum: reduce across the 4 quads (lane already holds its row's partial)
#pragma unroll
    for (int mt = 0; mt < 2; mt++) {
        float sm = l_loc[mt];
        sm += __shfl_xor(sm, 16);
        sm += __shfl_xor(sm, 32);
        l_loc[mt] = sm;
    }

    __bf16* Op = s ? Opart1 : Opart0;
    const long tb = (long)(h * 8 + qt) * 128 * 128;
#pragma unroll
    for (int mt = 0; mt < 2; mt++)
#pragma unroll
        for (int dt = 0; dt < 8; dt++)
#pragma unroll
            for (int r = 0; r < 4; r++)
                Op[tb + (long)(mt * 64 + w * 16 + quad * 4 + r) * 128 + dt * 16 + n] =
                    (__bf16)O[mt][dt][r];
    if (quad == 0) {
        const int lb = (s * 256 + h * 8 + qt) * 128 + w * 16;
#pragma unroll
        for (int mt = 0; mt < 2; mt++)
            lsum[lb + mt * 64 + n] = l_loc[mt];
    }
#undef KS
#undef PS
}

// ---------------------------------------------------------------------------
// Additive merge of split-K partials -> normalized bf16 attn-out.
// ---------------------------------------------------------------------------
__global__ __launch_bounds__(256) void flash_merge(const __bf16* __restrict__ O0,
                                                   const __bf16* __restrict__ O1,
                                                   const float* __restrict__ lsum,
                                                   __bf16* __restrict__ ob) {
    const int bx = blockIdx.x;         // 512: (h, qt, half64)
    const int h   = bx >> 4;
    const int r6  = bx & 15;
    const int qt  = r6 >> 1;
    const int sub = r6 & 1;
    const int row  = threadIdx.x >> 2;
    const int cseg = (threadIdx.x & 3) * 32;
    const int mrow = sub * 64 + row;

    const int tilei = h * 8 + qt;
    float inv = 1.0f / (lsum[tilei * 128 + mrow] + lsum[(256 + tilei) * 128 + mrow]);

    const long src = (long)tilei * 128 * 128 + (long)mrow * 128 + cseg;
    __bf16* dst = ob + (long)(qt * 128 + mrow) * 4096 + h * 128 + cseg;
#pragma unroll
    for (int j = 0; j < 4; j++) {
        bf16x8 x0 = *(const bf16x8*)(O0 + src + j * 8);
        bf16x8 x1 = *(const bf16x8*)(O1 + src + j * 8);
        bf16x8 o;
#pragma unroll
        for (int k = 0; k < 8; k++)
            o[k] = (__bf16)(((float)x0[k] + (float)x1[k]) * inv);
        *(bf16x8*)(dst + j * 8) = o;
    }
}

// ---------------------------------------------------------------------------
extern "C" void kernel_launch(void* const* d_in, const int* in_sizes, int n_in,
                              void* d_out, int out_size, void* d_ws, size_t ws_size,
                              hipStream_t stream) {
    const float* hidden = (const float*)d_in[0];
    const float* target = (const float*)d_in[1];
    const float* cosb   = (const float*)d_in[2];
    const float* sinb   = (const float*)d_in[3];
    const float* wq = (const float*)d_in[5];
    const float* wk = (const float*)d_in[6];
    const float* wv = (const float*)d_in[7];
    const float* wo = (const float*)d_in[8];
    const float* qw = (const float*)d_in[9];
    const float* kw = (const float*)d_in[10];
    float* out = (float*)d_out;

    // 40 MB workspace overlays (launch order guarantees safety). qbf and the
    // z=0 wo-partial live in d_out (dead region until the final add).
    char* ws = (char*)d_ws;
    const long MB = 1 << 20;
    __bf16* hidb = (__bf16*)(ws);             // @0..4    (dead after kvq)
    __bf16* tgtb = (__bf16*)(ws + 4 * MB);    // @4..12   (dead after kvq)
    __bf16* wkb  = (__bf16*)(ws + 12 * MB);   // @12..16  (dead after kvq)
    __bf16* wvb  = (__bf16*)(ws + 16 * MB);   // @16..20  (dead after kvq)
    __bf16* kbf  = (__bf16*)(ws + 20 * MB);   // @20..26  (dead after flash)
    __bf16* vbf  = (__bf16*)(ws + 26 * MB);   // @26..32  (dead after transpose)
    __bf16* vtg  = (__bf16*)(ws + 32 * MB);   // @32..38  (dead after flash)
    float*  lbuf = (float*)(ws);              // @0..0.25 (post-kvq)
    __bf16* Op0  = (__bf16*)(ws + 4 * MB);    // @4..12   (post-kvq; dead after merge)
    __bf16* Op1  = (__bf16*)(ws + 12 * MB);   // @12..20  (post-kvq; dead after merge)
    __bf16* attnb= (__bf16*)(ws + 20 * MB);   // @20..28  (post-flash)
    __bf16* wob0 = (__bf16*)(ws + 4 * MB);    // @4..12   (post-merge)
    __bf16* wob1 = (__bf16*)(ws + 12 * MB);   // @12..20  (post-merge)
    float*  po1  = (float*)(ws + 28 * MB);    // @28..36  (post-flash)
    __bf16* qbf  = (__bf16*)d_out;            // 8MB: q / dead after flash

    dim3 blk(256);

    // activations + k/v weights -> bf16
    conv4_f32_bf16<<<dim3(1024, 4), blk, 0, stream>>>(
        hidden, hidb, (1024 * 2048) / 4, target, tgtb, (2048 * 2048) / 4,
        wk, wkb, (1024 * 2048) / 4, wv, wvb, (1024 * 2048) / 4);

    // all three projections, one launch, all blocks resident
    gemm_kvq<<<640, blk, 0, stream>>>(tgtb, hidb, wkb, wvb, wq, kbf, vbf, qbf);

    // fused RMSNorm + RoPE (q and k)
    rmsnorm_rope2<<<dim3(8192, 2), blk, 0, stream>>>(qbf, qw, kbf, kw, cosb, sinb);

    // V transpose -> [g][d][t]
    transpose_v<<<dim3(48, 2, 8), blk, 0, stream>>>(vbf, vtg);

    // split-K flash attention (512 blocks, 128 q-rows each) + additive merge
    flash_attn_splitk<<<dim3(256, 2), blk, 0, stream>>>(qbf, kbf, vtg, Op0, Op1, lbuf);
    flash_merge<<<512, blk, 0, stream>>>(Op0, Op1, lbuf, attnb);

    // wo -> bf16 K-halves (Op0/Op1 space now dead), then split-K=2 projection
    conv_wo<<<2048, blk, 0, stream>>>(wo, wob0, wob1);
    gemm_wo2<<<dim3(16, 8, 2), blk, 0, stream>>>(attnb, wob0, wob1, out, po1);
    add2_inplace<<<1024, blk, 0, stream>>>(out, po1, (1024 * 2048) / 4);
}

// Round 3
// 358.447 us; speedup vs baseline: 1.0963x; 1.0042x over previous
//
#include <hip/hip_runtime.h>

#define HIDDEN 2048
#define NQ     1024
#define NCTX   2048
#define NTOT   3072
#define NHEADS 32
#define KVH    8
#define HD     128

typedef __attribute__((ext_vector_type(8))) __bf16 bf16x8;
typedef __attribute__((ext_vector_type(4))) __bf16 bf16x4;
typedef __attribute__((ext_vector_type(4))) float  f32x4;

#define MFMA16(a, b, c) __builtin_amdgcn_mfma_f32_16x16x32_bf16(a, b, c, 0, 0, 0)

// Fixed softmax shift (Cauchy-Schwarz: |q|=1 after folded 1/sqrt(d), |k|=sqrt(128),
// RoPE norm-preserving => s <= 11.4 incl. bf16 rounding).
#define MSTATIC 12.0f

__device__ __forceinline__ void load_lds16(const void* g, void* l) {
    __builtin_amdgcn_global_load_lds(
        (const __attribute__((address_space(1))) unsigned int*)g,
        (__attribute__((address_space(3))) unsigned int*)l, 16, 0, 0);
}

// ---------------------------------------------------------------------------
// 4-way fused fp32 -> bf16 convert (activations + k/v weights)
// ---------------------------------------------------------------------------
__global__ __launch_bounds__(256) void conv4_f32_bf16(const float* __restrict__ s0,
                                                      __bf16* __restrict__ d0, int n0,
                                                      const float* __restrict__ s1,
                                                      __bf16* __restrict__ d1, int n1,
                                                      const float* __restrict__ s2,
                                                      __bf16* __restrict__ d2, int n2,
                                                      const float* __restrict__ s3,
                                                      __bf16* __restrict__ d3, int n3) {
    const float* s; __bf16* d; int n;
    switch (blockIdx.y) {
        case 0:  s = s0; d = d0; n = n0; break;
        case 1:  s = s1; d = d1; n = n1; break;
        case 2:  s = s2; d = d2; n = n2; break;
        default: s = s3; d = d3; n = n3; break;
    }
    int i = blockIdx.x * 256 + threadIdx.x;
    int stride = gridDim.x * 256;
    for (; i < n; i += stride) {
        float4 v = ((const float4*)s)[i];
        bf16x4 o;
        o[0] = (__bf16)v.x; o[1] = (__bf16)v.y;
        o[2] = (__bf16)v.z; o[3] = (__bf16)v.w;
        ((bf16x4*)d)[i] = o;
    }
}

// wo (2048 x 4096) fp32 -> two bf16 K-halves (ld 2048), matching split-K blocks.
__global__ __launch_bounds__(256) void conv_wo(const float* __restrict__ wo,
                                               __bf16* __restrict__ w0,
                                               __bf16* __restrict__ w1) {
    int i = blockIdx.x * 256 + threadIdx.x;
    int stride = gridDim.x * 256;
    for (; i < 2048 * 1024; i += stride) {   // 1024 float4 per row
        int r = i >> 10, cc = i & 1023;
        float4 v = ((const float4*)wo)[i];
        bf16x4 o;
        o[0] = (__bf16)v.x; o[1] = (__bf16)v.y;
        o[2] = (__bf16)v.z; o[3] = (__bf16)v.w;
        __bf16* dst = (cc & 512) ? w1 : w0;
        *(bf16x4*)(dst + (long)r * 2048 + (cc & 511) * 4) = o;
    }
}

// ---------------------------------------------------------------------------
// 128x64 MFMA GEMM tile bodies. R10: the R9 counters showed the GEMMs are
// GRID-STARVED (Occupancy 14.6% with 640 blocks = 2.5/CU; LDS/VGPR not
// binding). N-tile 128->64 doubles the grid: kvq 1280 blocks (5/CU), wo 512
// (2/CU). Per-wave tile 64x32 (acc[4][2], ~85 VGPR, launch_bounds(256,5)).
// XOR bank-swizzle retained (R8-verified: conflicts 1.57e7 -> 0). B-weight
// traffic unchanged; A-refetch x2 is made L2-local by a bijective XCD
// swizzle with A-sharing tiles contiguous per XCD (T1, m204 form).
//   bb: both operands bf16, pure async global->LDS staging (zero VALU).
//   fb: A bf16 async; B fp32 reg-staged, LOAD one K-step ahead (T14).
// ---------------------------------------------------------------------------
__device__ __forceinline__ void gemm_compute6432(const __bf16 (&As)[128][64],
                                                 const __bf16 (&Bs)[64][64],
                                                 f32x4 (&acc)[4][2],
                                                 int wm, int wn, int n16, int quad, int rx) {
#pragma unroll
    for (int ks = 0; ks < 2; ks++) {
        bf16x8 af[4], bfr[2];
#pragma unroll
        for (int i = 0; i < 4; i++)
            af[i] = *(const bf16x8*)&As[wm + i * 16 + n16][((ks * 4 + quad) ^ rx) * 8];
#pragma unroll
        for (int j = 0; j < 2; j++)
            bfr[j] = *(const bf16x8*)&Bs[wn + j * 16 + n16][((ks * 4 + quad) ^ rx) * 8];
#pragma unroll
        for (int i = 0; i < 4; i++)
#pragma unroll
            for (int j = 0; j < 2; j++)
                acc[i][j] = MFMA16(af[i], bfr[j], acc[i][j]);
    }
}

template <typename OutT>
__device__ __forceinline__ void gemm_epilogue(const f32x4 (&acc)[4][2],
                                              OutT* __restrict__ Cblk, int ldc,
                                              int wm, int wn, int n16, int quad) {
#pragma unroll
    for (int i = 0; i < 4; i++)
#pragma unroll
        for (int j = 0; j < 2; j++)
#pragma unroll
            for (int r = 0; r < 4; r++)
                Cblk[(long)(wm + i * 16 + quad * 4 + r) * ldc + wn + j * 16 + n16] =
                    (OutT)acc[i][j][r];
}

template <typename OutT>
__device__ __forceinline__ void gemm6432_bb(__bf16 (&As)[128][64], __bf16 (&Bs)[64][64],
                                            const __bf16* __restrict__ Ablk,
                                            const __bf16* __restrict__ Bblk,
                                            OutT* __restrict__ Cblk,
                                            int K, int lda, int ldb, int ldc) {
    const int tid  = threadIdx.x;
    const int lane = tid & 63;
    const int w    = tid >> 6;
    const int n16  = lane & 15;
    const int quad = lane >> 4;
    const int wm = (w & 1) * 64;
    const int wn = (w >> 1) * 32;

    f32x4 acc[4][2];
    const f32x4 fzero = {0.f, 0.f, 0.f, 0.f};
#pragma unroll
    for (int i = 0; i < 4; i++)
#pragma unroll
        for (int j = 0; j < 2; j++) acc[i][j] = fzero;

    // Linear LDS dest (gload_lds requires wave-uniform base + lane*16);
    // source col pre-XORed so LDS[r][chunk c] holds global chunk c^(r&7).
    const int srow  = w * 32 + (lane >> 3);       // A rows, +8i (i=0..3)
    const int brow  = w * 16 + (lane >> 3);       // B rows, +8i (i=0..1)
    const int sxor  = (lane >> 3) & 7;            // == srow&7 == brow&7
    const int scol  = (lane & 7) * 8;
    const int sgcol = ((lane & 7) ^ sxor) * 8;
    const __bf16* Ap = Ablk + (long)srow * lda + sgcol;
    const __bf16* Bp = Bblk + (long)brow * ldb + sgcol;
    const int rx = n16 & 7;

    for (int k0 = 0; k0 < K; k0 += 64) {
#pragma unroll
        for (int i = 0; i < 4; i++)
            load_lds16(Ap + (long)i * 8 * lda + k0, &As[srow + i * 8][scol]);
#pragma unroll
        for (int i = 0; i < 2; i++)
            load_lds16(Bp + (long)i * 8 * ldb + k0, &Bs[brow + i * 8][scol]);
        __syncthreads();
        gemm_compute6432(As, Bs, acc, wm, wn, n16, quad, rx);
        __syncthreads();
    }
    gemm_epilogue(acc, Cblk, ldc, wm, wn, n16, quad);
}

template <typename OutT>
__device__ __forceinline__ void gemm6432_fb(__bf16 (&As)[128][64], __bf16 (&Bs)[64][64],
                                            const __bf16* __restrict__ Ablk,
                                            const float* __restrict__ Bblk,
                                            OutT* __restrict__ Cblk,
                                            int K, int lda, int ldb, int ldc) {
    const int tid  = threadIdx.x;
    const int lane = tid & 63;
    const int w    = tid >> 6;
    const int n16  = lane & 15;
    const int quad = lane >> 4;
    const int wm = (w & 1) * 64;
    const int wn = (w >> 1) * 32;

    f32x4 acc[4][2];
    const f32x4 fzero = {0.f, 0.f, 0.f, 0.f};
#pragma unroll
    for (int i = 0; i < 4; i++)
#pragma unroll
        for (int j = 0; j < 2; j++) acc[i][j] = fzero;

    const int srow  = w * 32 + (lane >> 3);
    const int sxor  = (lane >> 3) & 7;
    const int scol  = (lane & 7) * 8;
    const int sgcol = ((lane & 7) ^ sxor) * 8;
    const __bf16* Ap = Ablk + (long)srow * lda + sgcol;

    const int br0  = tid >> 3;                    // rows br0 + 32i (i=0..1)
    const int bxor = br0 & 7;                     // invariant under +32
    const int bgc  = (tid & 7) * 8;               // global col (floats)
    const int bwc  = ((tid & 7) ^ bxor) * 8;      // swizzled LDS write col
    const float* Bptr = Bblk + (long)br0 * ldb + bgc;

    const int rx = n16 & 7;
    float4 breg[2][2];

#define LOAD_B(kk)                                                             \
    _Pragma("unroll") for (int i = 0; i < 2; i++) {                            \
        breg[i][0] = *(const float4*)(Bptr + (long)i * 32 * ldb + (kk));       \
        breg[i][1] = *(const float4*)(Bptr + (long)i * 32 * ldb + (kk) + 4);   \
    }

    LOAD_B(0);
    for (int k0 = 0; k0 < K; k0 += 64) {
#pragma unroll
        for (int i = 0; i < 4; i++)
            load_lds16(Ap + (long)i * 8 * lda + k0, &As[srow + i * 8][scol]);
#pragma unroll
        for (int i = 0; i < 2; i++) {
            bf16x8 bb;
            bb[0] = (__bf16)breg[i][0].x; bb[1] = (__bf16)breg[i][0].y;
            bb[2] = (__bf16)breg[i][0].z; bb[3] = (__bf16)breg[i][0].w;
            bb[4] = (__bf16)breg[i][1].x; bb[5] = (__bf16)breg[i][1].y;
            bb[6] = (__bf16)breg[i][1].z; bb[7] = (__bf16)breg[i][1].w;
            *(bf16x8*)&Bs[br0 + i * 32][bwc] = bb;
        }
        if (k0 + 64 < K) LOAD_B(k0 + 64);   // in flight across compute below
        __syncthreads();
        gemm_compute6432(As, Bs, acc, wm, wn, n16, quad, rx);
        __syncthreads();
    }
#undef LOAD_B
    gemm_epilogue(acc, Cblk, ldc, wm, wn, n16, quad);
}

// ---------------------------------------------------------------------------
// Fused k + v + q projections, 1280 blocks (5/CU). XCD-swizzled so each XCD
// gets 160 contiguous logical tiles; tile order is m-major (consecutive
// logical tiles share the A-tile -> A-refetch stays in the XCD's L2).
// logical 0..383: k, 384..767: v (24m x 16n), 768..1279: q (8m x 64n).
// ---------------------------------------------------------------------------
__global__ __launch_bounds__(256, 5) void gemm_kvq(const __bf16* __restrict__ tgtb,
                                                   const __bf16* __restrict__ hidb,
                                                   const __bf16* __restrict__ wkb,
                                                   const __bf16* __restrict__ wvb,
                                                   const float* __restrict__ wq,
                                                   __bf16* __restrict__ kbf,
                                                   __bf16* __restrict__ vbf,
                                                   __bf16* __restrict__ qbf) {
    __shared__ __bf16 As[128][64];
    __shared__ __bf16 Bs[64][64];
    const int bid = blockIdx.x;
    const int b = (bid & 7) * 160 + (bid >> 3);   // bijective: 1280 = 8*160
    if (b < 768) {
        const int z = b >> 9 ? 1 : (b >= 384), t = b - z * 384;  // z = b/384
        const int m0 = (t >> 4) * 128, n0 = (t & 15) * 64;
        const __bf16* Ap = (m0 < 2048) ? tgtb + (long)m0 * 2048
                                       : hidb + (long)(m0 - 2048) * 2048;
        const __bf16* Bp = (z ? wvb : wkb) + (long)n0 * 2048;
        __bf16* Cp = (z ? vbf : kbf) + (long)m0 * 1024 + n0;
        gemm6432_bb<__bf16>(As, Bs, Ap, Bp, Cp, 2048, 2048, 2048, 1024);
    } else {
        const int t = b - 768;
        const int m0 = (t >> 6) * 128, n0 = (t & 63) * 64;
        gemm6432_fb<__bf16>(As, Bs, hidb + (long)m0 * 2048, wq + (long)n0 * 2048,
                            qbf + (long)m0 * 4096 + n0, 2048, 2048, 2048, 4096);
    }
}

// ---------------------------------------------------------------------------
// Output projection, split-K=2, 512 blocks (2/CU), XCD-swizzled m-major.
// z=0 partial straight to fp32 out; z=1 to po1; add2 sums.
// ---------------------------------------------------------------------------
__global__ __launch_bounds__(256, 5) void gemm_wo2(const __bf16* __restrict__ A,
                                                   const __bf16* __restrict__ w0,
                                                   const __bf16* __restrict__ w1,
                                                   float* __restrict__ out,
                                                   float* __restrict__ po1) {
    __shared__ __bf16 As[128][64];
    __shared__ __bf16 Bs[64][64];
    const int bid = blockIdx.x;
    const int b = (bid & 7) * 64 + (bid >> 3);    // bijective: 512 = 8*64
    const int z = b >> 8, t = b & 255;            // 8m x 32n per z
    const int m0 = (t >> 5) * 128, n0 = (t & 31) * 64;
    const __bf16* Bp = (z ? w1 : w0) + (long)n0 * 2048;
    float* C = (z ? po1 : out) + (long)m0 * 2048 + n0;
    gemm6432_bb<float>(As, Bs, A + (long)m0 * 4096 + z * 2048, Bp, C,
                       2048, 4096, 2048, 2048);
}

__global__ __launch_bounds__(256) void add2_inplace(float* __restrict__ out,
                                                    const float* __restrict__ p1, int n4) {
    int i = blockIdx.x * 256 + threadIdx.x;
    int stride = gridDim.x * 256;
    for (; i < n4; i += stride) {
        float4 a = ((const float4*)out)[i];
        float4 b = ((const float4*)p1)[i];
        float4 o;
        o.x = a.x + b.x; o.y = a.y + b.y;
        o.z = a.z + b.z; o.w = a.w + b.w;
        ((float4*)out)[i] = o;
    }
}

// ---------------------------------------------------------------------------
// Fused RMSNorm+RoPE for q (z=0) and k (z=1), in place.
// ---------------------------------------------------------------------------
__global__ __launch_bounds__(256) void rmsnorm_rope2(__bf16* __restrict__ xq,
                                                     const float* __restrict__ wq,
                                                     __bf16* __restrict__ xk,
                                                     const float* __restrict__ wk,
                                                     const float* __restrict__ cosb,
                                                     const float* __restrict__ sinb) {
    const int z = blockIdx.y;
    __bf16*      x = z ? xk : xq;
    const float* w = z ? wk : wq;
    const int nheads     = z ? 8 : 32;
    const int row_stride = z ? 1024 : 4096;
    const int pos_offset = z ? 0 : 2048;
    const float outscale = z ? 1.0f : 0.08838834764831845f;
    const int nitems     = z ? 3072 * 8 : 1024 * 32;

    int item = blockIdx.x * 4 + (threadIdx.x >> 6);
    int lane = threadIdx.x & 63;
    if (item >= nitems) return;
    int row = item / nheads;
    int head = item - row * nheads;
    __bf16* p = x + (long)row * row_stride + head * HD;

    float x1 = (float)p[lane], x2 = (float)p[lane + 64];
    float ss = x1 * x1 + x2 * x2;
#pragma unroll
    for (int o = 32; o >= 1; o >>= 1) ss += __shfl_xor(ss, o);
    float r = rsqrtf(ss * (1.0f / 128.0f) + 1e-6f) * outscale;

    int pos = pos_offset + row;
    float c1 = cosb[pos * HD + lane], c2 = cosb[pos * HD + lane + 64];
    float s1 = sinb[pos * HD + lane], s2 = sinb[pos * HD + lane + 64];
    float y1 = x1 * r * w[lane];
    float y2 = x2 * r * w[lane + 64];
    p[lane]      = (__bf16)(y1 * c1 - y2 * s1);
    p[lane + 64] = (__bf16)(y2 * c2 + y1 * s2);
}

// ---------------------------------------------------------------------------
// V transpose: vbf[t][g*128+d] -> vt[g][d][t]
// ---------------------------------------------------------------------------
__global__ __launch_bounds__(256) void transpose_v(const __bf16* __restrict__ v,
                                                   __bf16* __restrict__ vt) {
    __shared__ __bf16 T[64][68];
    const int tid = threadIdx.x;
    const int t0 = blockIdx.x * 64;
    const int d0 = blockIdx.y * 64;
    const int g  = blockIdx.z;
    const __bf16* src = v + (long)t0 * 1024 + g * 128 + d0;
#pragma unroll
    for (int i = 0; i < 4; i++) {
        int idx = tid + i * 256;
        int r = idx >> 4, c4 = (idx & 15) * 4;
        *(bf16x4*)&T[r][c4] = *(const bf16x4*)(src + (long)r * 1024 + c4);
    }
    __syncthreads();
    __bf16* dst = vt + (long)g * 128 * 3072 + (long)d0 * 3072 + t0;
#pragma unroll
    for (int i = 0; i < 4; i++) {
        int idx = tid + i * 256;
        int r = idx >> 4, c4 = (idx & 15) * 4;
        bf16x4 o;
        o[0] = T[c4 + 0][r]; o[1] = T[c4 + 1][r];
        o[2] = T[c4 + 2][r]; o[3] = T[c4 + 3][r];
        *(bf16x4*)(dst + (long)r * 3072 + c4) = o;
    }
}

// ---------------------------------------------------------------------------
// Split-K flash attention, 128 q-rows per block (4 waves x 2 m-tiles of 16).
// S computed TRANSPOSED (S^T = K Q^T, pure operand swap: A/B fragment lane
// layouts are identical for 16x16x32) so P exits with t in the register
// direction -> P->LDS is 8 packed ds_write_b64 per wave-tile instead of 32
// scalar b16 writes, and the row-sum is lane-local. PV phase, O layout,
// epilogue and merge are unchanged. Ps aliases Ks (stride 68).
// ---------------------------------------------------------------------------
__global__ __launch_bounds__(256) void flash_attn_splitk(const __bf16* __restrict__ qb,
                                                         const __bf16* __restrict__ kb,
                                                         const __bf16* __restrict__ vtg,
                                                         __bf16* __restrict__ Opart0,
                                                         __bf16* __restrict__ Opart1,
                                                         float* __restrict__ lsum) {
    __shared__ __bf16 KsU[64 * 136];   // Ks[t][d] stride 136; Ps aliased (4*32*68 = 8704)
    __shared__ __bf16 Vs[128][72];     // [d][t]
#define KS(r, c) KsU[(r) * 136 + (c)]
#define PS(w_, m_, t_) KsU[(w_) * 2176 + (m_) * 68 + (t_)]

    const int tid  = threadIdx.x;
    const int lane = tid & 63;
    const int w    = tid >> 6;
    const int n    = lane & 15;
    const int quad = lane >> 4;

    const int bid = blockIdx.x;        // 0..255
    const int s   = blockIdx.y;
    const int g  = bid & 7;
    const int jj = bid >> 3;           // 0..31
    const int h  = g * 4 + (jj & 3);
    const int qt = jj >> 2;            // 0..7, 128-row q tiles

    const int qr0 = qt * 128 + w * 16; // m-tile 0 base; m-tile 1 = +64

    bf16x8 qf[2][4];
#pragma unroll
    for (int mt = 0; mt < 2; mt++) {
        const __bf16* qp = qb + (long)(qr0 + mt * 64 + n) * 4096 + h * 128 + quad * 8;
        qf[mt][0] = *(const bf16x8*)(qp);
        qf[mt][1] = *(const bf16x8*)(qp + 32);
        qf[mt][2] = *(const bf16x8*)(qp + 64);
        qf[mt][3] = *(const bf16x8*)(qp + 96);
    }

    f32x4 O[2][8];
    const f32x4 fzero = {0.f, 0.f, 0.f, 0.f};
#pragma unroll
    for (int mt = 0; mt < 2; mt++)
#pragma unroll
        for (int dt = 0; dt < 8; dt++) O[mt][dt] = fzero;
    float l_loc[2] = {0.f, 0.f};       // lane-local: lane n16 owns q-row qr0+mt*64+n

    const int ntot = 34 + 2 * qt;      // even
    const int half = ntot >> 1;
    const int tbeg = s ? half : 0;
    const int tend = s ? ntot : half;

    const int krr = tid >> 4, kc8 = (tid & 15) * 8;
    const int vrr = tid >> 3, vc8 = (tid & 7) * 8;
    const __bf16* kp = kb + g * 128 + (long)(tbeg * 64 + krr) * 1024 + kc8;
    const __bf16* vp = vtg + (long)g * 128 * 3072 + (long)vrr * 3072 + tbeg * 64 + vc8;

    for (int tt = tbeg; tt < tend; tt++) {
#pragma unroll
        for (int i = 0; i < 4; i++)
            *(bf16x8*)&KS(krr + i * 16, kc8) = *(const bf16x8*)(kp + (long)i * 16 * 1024);
#pragma unroll
        for (int i = 0; i < 4; i++)
            *(bf16x8*)&Vs[vrr + i * 32][vc8] = *(const bf16x8*)(vp + (long)i * 32 * 3072);
        kp += 64 * 1024;
        vp += 64;
        __syncthreads();

        // S^T = K Q^T: A = K-frag, B = Q-frag (identical lane layouts).
        // Result: col(lane&15) = q-row, row(quad*4+r) = key t.
        f32x4 S[2][4];
#pragma unroll
        for (int nt = 0; nt < 4; nt++) {
            f32x4 a0 = fzero, a1 = fzero;
#pragma unroll
            for (int ks = 0; ks < 4; ks++) {
                bf16x8 kf = *(const bf16x8*)&KS(nt * 16 + n, ks * 32 + quad * 8);
                a0 = MFMA16(kf, qf[0][ks], a0);
                a1 = MFMA16(kf, qf[1][ks], a1);
            }
            S[0][nt] = a0;
            S[1][nt] = a1;
        }

        if (tt >= ntot - 2) {   // diagonal band spans the last two tiles
            const int t0 = tt * 64;
#pragma unroll
            for (int mt = 0; mt < 2; mt++) {
                const int lim = 2048 + qr0 + mt * 64 + n;   // q-row = lane index
#pragma unroll
                for (int nt = 0; nt < 4; nt++)
#pragma unroll
                    for (int r = 0; r < 4; r++) {
                        int t = t0 + nt * 16 + quad * 4 + r;
                        if (t > lim) S[mt][nt][r] = -1e30f;
                    }
            }
        }

        __syncthreads();   // all Ks reads done; Ps may overwrite

        // fixed-shift softmax; row-sum is lane-local (lane owns its q-row)
#pragma unroll
        for (int mt = 0; mt < 2; mt++)
#pragma unroll
            for (int nt = 0; nt < 4; nt++)
#pragma unroll
                for (int r = 0; r < 4; r++) {
                    float p = __expf(S[mt][nt][r] - MSTATIC);
                    S[mt][nt][r] = p;
                    l_loc[mt] += p;
                }

        // P -> LDS: packed b64 writes (4 consecutive t per (mt,nt))
#pragma unroll
        for (int mt = 0; mt < 2; mt++)
#pragma unroll
            for (int nt = 0; nt < 4; nt++) {
                bf16x4 pk;
#pragma unroll
                for (int r = 0; r < 4; r++) pk[r] = (__bf16)S[mt][nt][r];
                *(bf16x4*)&PS(w, mt * 16 + n, nt * 16 + quad * 4) = pk;
            }

        bf16x8 pa[2][2];
#pragma unroll
        for (int mt = 0; mt < 2; mt++)
#pragma unroll
            for (int kg = 0; kg < 2; kg++)
                pa[mt][kg] = *(const bf16x8*)&PS(w, mt * 16 + n, kg * 32 + quad * 8);

#pragma unroll
        for (int dt = 0; dt < 8; dt++) {
            bf16x8 vf0 = *(const bf16x8*)&Vs[dt * 16 + n][quad * 8];
            bf16x8 vf1 = *(const bf16x8*)&Vs[dt * 16 + n][32 + quad * 8];
#pragma unroll
            for (int mt = 0; mt < 2; mt++) {
                f32x4 acc = O[mt][dt];
                acc = MFMA16(pa[mt][0], vf0, acc);
                acc = MFMA16(pa[mt][1], vf1, acc);
                O[mt][dt] = acc;
            }
        }
        __syncthreads();
    }

    // row-sum: reduce across the 4 quads (lane already holds its row's partial)
#pragma unroll
    for (int mt = 0; mt < 2; mt++) {
        float sm = l_loc[mt];
        sm += __shfl_xor(sm, 16);
        sm += __shfl_xor(sm, 32);
        l_loc[mt] = sm;
    }

    __bf16* Op = s ? Opart1 : Opart0;
    const long tb = (long)(h * 8 + qt) * 128 * 128;
#pragma unroll
    for (int mt = 0; mt < 2; mt++)
#pragma unroll
        for (int dt = 0; dt < 8; dt++)
#pragma unroll
            for (int r = 0; r < 4; r++)
                Op[tb + (long)(mt * 64 + w * 16 + quad * 4 + r) * 128 + dt * 16 + n] =
                    (__bf16)O[mt][dt][r];
    if (quad == 0) {
        const int lb = (s * 256 + h * 8 + qt) * 128 + w * 16;
#pragma unroll
        for (int mt = 0; mt < 2; mt++)
            lsum[lb + mt * 64 + n] = l_loc[mt];
    }
#undef KS
#undef PS
}

// ---------------------------------------------------------------------------
// Additive merge of split-K partials -> normalized bf16 attn-out.
// ---------------------------------------------------------------------------
__global__ __launch_bounds__(256) void flash_merge(const __bf16* __restrict__ O0,
                                                   const __bf16* __restrict__ O1,
                                                   const float* __restrict__ lsum,
                                                   __bf16* __restrict__ ob) {
    const int bx = blockIdx.x;         // 512: (h, qt, half64)
    const int h   = bx >> 4;
    const int r6  = bx & 15;
    const int qt  = r6 >> 1;
    const int sub = r6 & 1;
    const int row  = threadIdx.x >> 2;
    const int cseg = (threadIdx.x & 3) * 32;
    const int mrow = sub * 64 + row;

    const int tilei = h * 8 + qt;
    float inv = 1.0f / (lsum[tilei * 128 + mrow] + lsum[(256 + tilei) * 128 + mrow]);

    const long src = (long)tilei * 128 * 128 + (long)mrow * 128 + cseg;
    __bf16* dst = ob + (long)(qt * 128 + mrow) * 4096 + h * 128 + cseg;
#pragma unroll
    for (int j = 0; j < 4; j++) {
        bf16x8 x0 = *(const bf16x8*)(O0 + src + j * 8);
        bf16x8 x1 = *(const bf16x8*)(O1 + src + j * 8);
        bf16x8 o;
#pragma unroll
        for (int k = 0; k < 8; k++)
            o[k] = (__bf16)(((float)x0[k] + (float)x1[k]) * inv);
        *(bf16x8*)(dst + j * 8) = o;
    }
}

// ---------------------------------------------------------------------------
extern "C" void kernel_launch(void* const* d_in, const int* in_sizes, int n_in,
                              void* d_out, int out_size, void* d_ws, size_t ws_size,
                              hipStream_t stream) {
    const float* hidden = (const float*)d_in[0];
    const float* target = (const float*)d_in[1];
    const float* cosb   = (const float*)d_in[2];
    const float* sinb   = (const float*)d_in[3];
    const float* wq = (const float*)d_in[5];
    const float* wk = (const float*)d_in[6];
    const float* wv = (const float*)d_in[7];
    const float* wo = (const float*)d_in[8];
    const float* qw = (const float*)d_in[9];
    const float* kw = (const float*)d_in[10];
    float* out = (float*)d_out;

    // 40 MB workspace overlays (launch order guarantees safety). qbf and the
    // z=0 wo-partial live in d_out (dead region until the final add).
    char* ws = (char*)d_ws;
    const long MB = 1 << 20;
    __bf16* hidb = (__bf16*)(ws);             // @0..4    (dead after kvq)
    __bf16* tgtb = (__bf16*)(ws + 4 * MB);    // @4..12   (dead after kvq)
    __bf16* wkb  = (__bf16*)(ws + 12 * MB);   // @12..16  (dead after kvq)
    __bf16* wvb  = (__bf16*)(ws + 16 * MB);   // @16..20  (dead after kvq)
    __bf16* kbf  = (__bf16*)(ws + 20 * MB);   // @20..26  (dead after flash)
    __bf16* vbf  = (__bf16*)(ws + 26 * MB);   // @26..32  (dead after transpose)
    __bf16* vtg  = (__bf16*)(ws + 32 * MB);   // @32..38  (dead after flash)
    float*  lbuf = (float*)(ws);              // @0..0.25 (post-kvq)
    __bf16* Op0  = (__bf16*)(ws + 4 * MB);    // @4..12   (post-kvq; dead after merge)
    __bf16* Op1  = (__bf16*)(ws + 12 * MB);   // @12..20  (post-kvq; dead after merge)
    __bf16* attnb= (__bf16*)(ws + 20 * MB);   // @20..28  (post-flash)
    __bf16* wob0 = (__bf16*)(ws + 4 * MB);    // @4..12   (post-merge)
    __bf16* wob1 = (__bf16*)(ws + 12 * MB);   // @12..20  (post-merge)
    float*  po1  = (float*)(ws + 28 * MB);    // @28..36  (post-flash)
    __bf16* qbf  = (__bf16*)d_out;            // 8MB: q / dead after flash

    dim3 blk(256);

    // activations + k/v weights -> bf16
    conv4_f32_bf16<<<dim3(1024, 4), blk, 0, stream>>>(
        hidden, hidb, (1024 * 2048) / 4, target, tgtb, (2048 * 2048) / 4,
        wk, wkb, (1024 * 2048) / 4, wv, wvb, (1024 * 2048) / 4);

    // all three projections, one launch, 1280 blocks = 5/CU
    gemm_kvq<<<1280, blk, 0, stream>>>(tgtb, hidb, wkb, wvb, wq, kbf, vbf, qbf);

    // fused RMSNorm + RoPE (q and k)
    rmsnorm_rope2<<<dim3(8192, 2), blk, 0, stream>>>(qbf, qw, kbf, kw, cosb, sinb);

    // V transpose -> [g][d][t]
    transpose_v<<<dim3(48, 2, 8), blk, 0, stream>>>(vbf, vtg);

    // split-K flash attention (512 blocks, 128 q-rows each) + additive merge
    flash_attn_splitk<<<dim3(256, 2), blk, 0, stream>>>(qbf, kbf, vtg, Op0, Op1, lbuf);
    flash_merge<<<512, blk, 0, stream>>>(Op0, Op1, lbuf, attnb);

    // wo -> bf16 K-halves (Op0/Op1 space now dead), then split-K=2 projection
    conv_wo<<<2048, blk, 0, stream>>>(wo, wob0, wob1);
    gemm_wo2<<<512, blk, 0, stream>>>(attnb, wob0, wob1, out, po1);
    add2_inplace<<<1024, blk, 0, stream>>>(out, po1, (1024 * 2048) / 4);
}

// Round 5
// 338.552 us; speedup vs baseline: 1.1607x; 1.0588x over previous
//
#include <hip/hip_runtime.h>

#define HIDDEN 2048
#define NQ     1024
#define NCTX   2048
#define NTOT   3072
#define NHEADS 32
#define KVH    8
#define HD     128

typedef __attribute__((ext_vector_type(8))) __bf16 bf16x8;
typedef __attribute__((ext_vector_type(4))) __bf16 bf16x4;
typedef __attribute__((ext_vector_type(4))) float  f32x4;

#define MFMA16(a, b, c) __builtin_amdgcn_mfma_f32_16x16x32_bf16(a, b, c, 0, 0, 0)

// Fixed softmax shift (Cauchy-Schwarz: |q|=1 after folded 1/sqrt(d), |k|=sqrt(128),
// RoPE norm-preserving => s <= 11.4 incl. bf16 rounding).
#define MSTATIC 12.0f

__device__ __forceinline__ void load_lds16(const void* g, void* l) {
    __builtin_amdgcn_global_load_lds(
        (const __attribute__((address_space(1))) unsigned int*)g,
        (__attribute__((address_space(3))) unsigned int*)l, 16, 0, 0);
}

// ---------------------------------------------------------------------------
// 4-way fused fp32 -> bf16 convert (activations + k/v weights)
// ---------------------------------------------------------------------------
__global__ __launch_bounds__(256) void conv4_f32_bf16(const float* __restrict__ s0,
                                                      __bf16* __restrict__ d0, int n0,
                                                      const float* __restrict__ s1,
                                                      __bf16* __restrict__ d1, int n1,
                                                      const float* __restrict__ s2,
                                                      __bf16* __restrict__ d2, int n2,
                                                      const float* __restrict__ s3,
                                                      __bf16* __restrict__ d3, int n3) {
    const float* s; __bf16* d; int n;
    switch (blockIdx.y) {
        case 0:  s = s0; d = d0; n = n0; break;
        case 1:  s = s1; d = d1; n = n1; break;
        case 2:  s = s2; d = d2; n = n2; break;
        default: s = s3; d = d3; n = n3; break;
    }
    int i = blockIdx.x * 256 + threadIdx.x;
    int stride = gridDim.x * 256;
    for (; i < n; i += stride) {
        float4 v = ((const float4*)s)[i];
        bf16x4 o;
        o[0] = (__bf16)v.x; o[1] = (__bf16)v.y;
        o[2] = (__bf16)v.z; o[3] = (__bf16)v.w;
        ((bf16x4*)d)[i] = o;
    }
}

// ---------------------------------------------------------------------------
// 256x64 MFMA GEMM tile bodies. R11/R12: R10 counters showed the GEMMs are
// DELIVERY-bound (983 MB staged via L2/L3 at ~11 TB/s; MfmaUtil 19% flat
// despite 2x occupancy; HBM 25%, VALU 11%, conflicts 0). 256x64 tiles cut
// staged bytes/FLOP 23 -> 9.8 B/KFLOP (per-wave 64x64 = m97's proven inner
// shape: acc[4][4], 32 MFMA/K-step). LDS 40KB -> 4 blocks/CU; kvq grid 640
// all-resident. XOR bank-swizzle retained (R8-verified: conflicts -> 0):
// linear LDS dest (gload_lds requirement) + pre-swizzled global source +
// swizzled read. R12 = R11 resubmit: container failure was infra-side
// (audit: bounds / LDS=160KB / barrier-uniformity / lds-dest-linearity /
// overlay liveness all verified clean).
//   bb: both operands bf16, pure async global->LDS staging (zero VALU).
//   fb: A bf16 async; B fp32 reg-staged one K-step ahead (T14), cvt->LDS.
// ---------------------------------------------------------------------------
__device__ __forceinline__ void gemm_compute256(const __bf16 (&As)[256][64],
                                                const __bf16 (&Bs)[64][64],
                                                f32x4 (&acc)[4][4],
                                                int wm, int n16, int quad, int rx) {
#pragma unroll
    for (int ks = 0; ks < 2; ks++) {
        bf16x8 af[4], bfr[4];
#pragma unroll
        for (int i = 0; i < 4; i++)
            af[i] = *(const bf16x8*)&As[wm + i * 16 + n16][((ks * 4 + quad) ^ rx) * 8];
#pragma unroll
        for (int j = 0; j < 4; j++)
            bfr[j] = *(const bf16x8*)&Bs[j * 16 + n16][((ks * 4 + quad) ^ rx) * 8];
#pragma unroll
        for (int i = 0; i < 4; i++)
#pragma unroll
            for (int j = 0; j < 4; j++)
                acc[i][j] = MFMA16(af[i], bfr[j], acc[i][j]);
    }
}

template <typename OutT>
__device__ __forceinline__ void gemm_epi256(const f32x4 (&acc)[4][4],
                                            OutT* __restrict__ Cblk, int ldc,
                                            int wm, int n16, int quad) {
#pragma unroll
    for (int i = 0; i < 4; i++)
#pragma unroll
        for (int j = 0; j < 4; j++)
#pragma unroll
            for (int r = 0; r < 4; r++)
                Cblk[(long)(wm + i * 16 + quad * 4 + r) * ldc + j * 16 + n16] =
                    (OutT)acc[i][j][r];
}

template <typename OutT>
__device__ __forceinline__ void gemm25664_bb(__bf16 (&As)[256][64], __bf16 (&Bs)[64][64],
                                             const __bf16* __restrict__ Ablk,
                                             const __bf16* __restrict__ Bblk,
                                             OutT* __restrict__ Cblk,
                                             int K, int lda, int ldb, int ldc) {
    const int tid  = threadIdx.x;
    const int lane = tid & 63;
    const int w    = tid >> 6;
    const int n16  = lane & 15;
    const int quad = lane >> 4;
    const int wm   = w * 64;                      // wave's 64-row m-slab

    f32x4 acc[4][4];
    const f32x4 fzero = {0.f, 0.f, 0.f, 0.f};
#pragma unroll
    for (int i = 0; i < 4; i++)
#pragma unroll
        for (int j = 0; j < 4; j++) acc[i][j] = fzero;

    // Linear LDS dest (gload_lds: wave-uniform base + lane*16); source col
    // pre-XORed so LDS[r][chunk c] holds global chunk c^(r&7).
    const int arow  = w * 64 + (lane >> 3);       // A rows, +8i (i=0..7)
    const int brow  = w * 16 + (lane >> 3);       // B rows, +8i (i=0..1)
    const int sxor  = (lane >> 3) & 7;            // == arow&7 == brow&7
    const int scol  = (lane & 7) * 8;
    const int sgcol = ((lane & 7) ^ sxor) * 8;
    const __bf16* Ap = Ablk + (long)arow * lda + sgcol;
    const __bf16* Bp = Bblk + (long)brow * ldb + sgcol;
    const int rx = n16 & 7;

    for (int k0 = 0; k0 < K; k0 += 64) {
#pragma unroll
        for (int i = 0; i < 8; i++)
            load_lds16(Ap + (long)i * 8 * lda + k0, &As[arow + i * 8][scol]);
#pragma unroll
        for (int i = 0; i < 2; i++)
            load_lds16(Bp + (long)i * 8 * ldb + k0, &Bs[brow + i * 8][scol]);
        __syncthreads();
        gemm_compute256(As, Bs, acc, wm, n16, quad, rx);
        __syncthreads();
    }
    gemm_epi256(acc, Cblk, ldc, wm, n16, quad);
}

template <typename OutT>
__device__ __forceinline__ void gemm25664_fb(__bf16 (&As)[256][64], __bf16 (&Bs)[64][64],
                                             const __bf16* __restrict__ Ablk,
                                             const float* __restrict__ Bblk,
                                             OutT* __restrict__ Cblk,
                                             int K, int lda, int ldb, int ldc) {
    const int tid  = threadIdx.x;
    const int lane = tid & 63;
    const int w    = tid >> 6;
    const int n16  = lane & 15;
    const int quad = lane >> 4;
    const int wm   = w * 64;

    f32x4 acc[4][4];
    const f32x4 fzero = {0.f, 0.f, 0.f, 0.f};
#pragma unroll
    for (int i = 0; i < 4; i++)
#pragma unroll
        for (int j = 0; j < 4; j++) acc[i][j] = fzero;

    const int arow  = w * 64 + (lane >> 3);
    const int sxor  = (lane >> 3) & 7;
    const int scol  = (lane & 7) * 8;
    const int sgcol = ((lane & 7) ^ sxor) * 8;
    const __bf16* Ap = Ablk + (long)arow * lda + sgcol;

    // B: one row per thread (64 rows x 64 fp32 cols = 16 consecutive floats
    // per thread), reg-staged, cvt->bf16, swizzled ds_write (2 chunks).
    const int brr  = tid >> 2;                    // B row 0..63
    const int bc0  = (tid & 3) * 16;              // first of 16 fp32 cols
    const int bch  = (tid & 3) * 2;               // first of 2 bf16x8 chunks
    const int bxor = brr & 7;
    const float* Bptr = Bblk + (long)brr * ldb + bc0;

    const int rx = n16 & 7;
    float4 breg[4];

#define LOAD_B(kk)                                                             \
    _Pragma("unroll") for (int i = 0; i < 4; i++)                              \
        breg[i] = *(const float4*)(Bptr + (kk) + i * 4);

    LOAD_B(0);
    for (int k0 = 0; k0 < K; k0 += 64) {
#pragma unroll
        for (int i = 0; i < 8; i++)
            load_lds16(Ap + (long)i * 8 * lda + k0, &As[arow + i * 8][scol]);
        {
            bf16x8 b0, b1;
#pragma unroll
            for (int j = 0; j < 4; j++) {
                b0[j]     = (__bf16)breg[0][j]; b0[j + 4] = (__bf16)breg[1][j];
                b1[j]     = (__bf16)breg[2][j]; b1[j + 4] = (__bf16)breg[3][j];
            }
            *(bf16x8*)&Bs[brr][((bch + 0) ^ bxor) * 8] = b0;
            *(bf16x8*)&Bs[brr][((bch + 1) ^ bxor) * 8] = b1;
        }
        if (k0 + 64 < K) LOAD_B(k0 + 64);   // in flight across compute below
        __syncthreads();
        gemm_compute256(As, Bs, acc, wm, n16, quad, rx);
        __syncthreads();
    }
#undef LOAD_B
    gemm_epi256(acc, Cblk, ldc, wm, n16, quad);
}

// ---------------------------------------------------------------------------
// Fused k + v + q projections, 640 blocks (all resident at 4/CU LDS cap).
// logical 0..191: k (12m x 16n), 192..383: v, 384..639: q (4m x 64n).
// m-major ordering + chunked XCD swizzle keeps A-panels L2-local.
// ---------------------------------------------------------------------------
__global__ __launch_bounds__(256, 4) void gemm_kvq(const __bf16* __restrict__ tgtb,
                                                   const __bf16* __restrict__ hidb,
                                                   const __bf16* __restrict__ wkb,
                                                   const __bf16* __restrict__ wvb,
                                                   const float* __restrict__ wq,
                                                   __bf16* __restrict__ kbf,
                                                   __bf16* __restrict__ vbf,
                                                   __bf16* __restrict__ qbf) {
    __shared__ __bf16 As[256][64];
    __shared__ __bf16 Bs[64][64];
    const int bid = blockIdx.x;
    const int b = (bid & 7) * 80 + (bid >> 3);    // bijective: 640 = 8*80
    if (b < 384) {
        const int z = b >= 192, t = b - z * 192;
        const int m0 = (t >> 4) * 256, n0 = (t & 15) * 64;
        const __bf16* Ap = (m0 < 2048) ? tgtb + (long)m0 * 2048
                                       : hidb + (long)(m0 - 2048) * 2048;
        const __bf16* Bp = (z ? wvb : wkb) + (long)n0 * 2048;
        __bf16* Cp = (z ? vbf : kbf) + (long)m0 * 1024 + n0;
        gemm25664_bb<__bf16>(As, Bs, Ap, Bp, Cp, 2048, 2048, 2048, 1024);
    } else {
        const int t = b - 384;
        const int m0 = (t >> 6) * 256, n0 = (t & 63) * 64;
        gemm25664_fb<__bf16>(As, Bs, hidb + (long)m0 * 2048, wq + (long)n0 * 2048,
                             qbf + (long)m0 * 4096 + n0, 2048, 2048, 2048, 4096);
    }
}

// ---------------------------------------------------------------------------
// Output projection: 256x64 tiles, split-K=4, B = fp32 wo direct (fb path,
// no conversion pre-pass). 512 blocks (2/CU), K=1024 (16 steps) each.
// z=0 partial straight to fp32 out; z=1..3 to ws partials; add4 sums.
// ---------------------------------------------------------------------------
__global__ __launch_bounds__(256, 4) void gemm_wo4(const __bf16* __restrict__ A,
                                                   const float* __restrict__ wo,
                                                   float* __restrict__ out,
                                                   float* __restrict__ p1,
                                                   float* __restrict__ p2,
                                                   float* __restrict__ p3) {
    __shared__ __bf16 As[256][64];
    __shared__ __bf16 Bs[64][64];
    const int bid = blockIdx.x;
    const int b = (bid & 7) * 64 + (bid >> 3);    // bijective: 512 = 8*64
    const int z = b >> 7, t = b & 127;            // 4m x 32n per z
    const int m0 = (t >> 5) * 256, n0 = (t & 31) * 64;
    float* C;
    switch (z) {
        case 0:  C = out; break;
        case 1:  C = p1;  break;
        case 2:  C = p2;  break;
        default: C = p3;  break;
    }
    gemm25664_fb<float>(As, Bs, A + (long)m0 * 4096 + z * 1024,
                        wo + (long)n0 * 4096 + z * 1024,
                        C + (long)m0 * 2048 + n0, 1024, 4096, 4096, 2048);
}

__global__ __launch_bounds__(256) void add4_wo(float* __restrict__ out,
                                               const float* __restrict__ p1,
                                               const float* __restrict__ p2,
                                               const float* __restrict__ p3, int n4) {
    int i = blockIdx.x * 256 + threadIdx.x;
    int stride = gridDim.x * 256;
    for (; i < n4; i += stride) {
        float4 a = ((const float4*)out)[i];
        float4 b = ((const float4*)p1)[i];
        float4 c = ((const float4*)p2)[i];
        float4 d = ((const float4*)p3)[i];
        float4 o;
        o.x = (a.x + b.x) + (c.x + d.x);
        o.y = (a.y + b.y) + (c.y + d.y);
        o.z = (a.z + b.z) + (c.z + d.z);
        o.w = (a.w + b.w) + (c.w + d.w);
        ((float4*)out)[i] = o;
    }
}

// ---------------------------------------------------------------------------
// Fused RMSNorm+RoPE for q (z=0) and k (z=1), in place.
// ---------------------------------------------------------------------------
__global__ __launch_bounds__(256) void rmsnorm_rope2(__bf16* __restrict__ xq,
                                                     const float* __restrict__ wq,
                                                     __bf16* __restrict__ xk,
                                                     const float* __restrict__ wk,
                                                     const float* __restrict__ cosb,
                                                     const float* __restrict__ sinb) {
    const int z = blockIdx.y;
    __bf16*      x = z ? xk : xq;
    const float* w = z ? wk : wq;
    const int nheads     = z ? 8 : 32;
    const int row_stride = z ? 1024 : 4096;
    const int pos_offset = z ? 0 : 2048;
    const float outscale = z ? 1.0f : 0.08838834764831845f;
    const int nitems     = z ? 3072 * 8 : 1024 * 32;

    int item = blockIdx.x * 4 + (threadIdx.x >> 6);
    int lane = threadIdx.x & 63;
    if (item >= nitems) return;
    int row = item / nheads;
    int head = item - row * nheads;
    __bf16* p = x + (long)row * row_stride + head * HD;

    float x1 = (float)p[lane], x2 = (float)p[lane + 64];
    float ss = x1 * x1 + x2 * x2;
#pragma unroll
    for (int o = 32; o >= 1; o >>= 1) ss += __shfl_xor(ss, o);
    float r = rsqrtf(ss * (1.0f / 128.0f) + 1e-6f) * outscale;

    int pos = pos_offset + row;
    float c1 = cosb[pos * HD + lane], c2 = cosb[pos * HD + lane + 64];
    float s1 = sinb[pos * HD + lane], s2 = sinb[pos * HD + lane + 64];
    float y1 = x1 * r * w[lane];
    float y2 = x2 * r * w[lane + 64];
    p[lane]      = (__bf16)(y1 * c1 - y2 * s1);
    p[lane + 64] = (__bf16)(y2 * c2 + y1 * s2);
}

// ---------------------------------------------------------------------------
// V transpose: vbf[t][g*128+d] -> vt[g][d][t]
// ---------------------------------------------------------------------------
__global__ __launch_bounds__(256) void transpose_v(const __bf16* __restrict__ v,
                                                   __bf16* __restrict__ vt) {
    __shared__ __bf16 T[64][68];
    const int tid = threadIdx.x;
    const int t0 = blockIdx.x * 64;
    const int d0 = blockIdx.y * 64;
    const int g  = blockIdx.z;
    const __bf16* src = v + (long)t0 * 1024 + g * 128 + d0;
#pragma unroll
    for (int i = 0; i < 4; i++) {
        int idx = tid + i * 256;
        int r = idx >> 4, c4 = (idx & 15) * 4;
        *(bf16x4*)&T[r][c4] = *(const bf16x4*)(src + (long)r * 1024 + c4);
    }
    __syncthreads();
    __bf16* dst = vt + (long)g * 128 * 3072 + (long)d0 * 3072 + t0;
#pragma unroll
    for (int i = 0; i < 4; i++) {
        int idx = tid + i * 256;
        int r = idx >> 4, c4 = (idx & 15) * 4;
        bf16x4 o;
        o[0] = T[c4 + 0][r]; o[1] = T[c4 + 1][r];
        o[2] = T[c4 + 2][r]; o[3] = T[c4 + 3][r];
        *(bf16x4*)(dst + (long)r * 3072 + c4) = o;
    }
}

// ---------------------------------------------------------------------------
// Split-K flash attention, 128 q-rows per block (4 waves x 2 m-tiles of 16).
// S computed TRANSPOSED (S^T = K Q^T, pure operand swap: A/B fragment lane
// layouts are identical for 16x16x32) so P exits with t in the register
// direction -> P->LDS is 8 packed ds_write_b64 per wave-tile instead of 32
// scalar b16 writes, and the row-sum is lane-local. PV phase, O layout,
// epilogue and merge are unchanged. Ps aliases Ks (stride 68).
// ---------------------------------------------------------------------------
__global__ __launch_bounds__(256) void flash_attn_splitk(const __bf16* __restrict__ qb,
                                                         const __bf16* __restrict__ kb,
                                                         const __bf16* __restrict__ vtg,
                                                         __bf16* __restrict__ Opart0,
                                                         __bf16* __restrict__ Opart1,
                                                         float* __restrict__ lsum) {
    __shared__ __bf16 KsU[64 * 136];   // Ks[t][d] stride 136; Ps aliased (4*32*68 = 8704)
    __shared__ __bf16 Vs[128][72];     // [d][t]
#define KS(r, c) KsU[(r) * 136 + (c)]
#define PS(w_, m_, t_) KsU[(w_) * 2176 + (m_) * 68 + (t_)]

    const int tid  = threadIdx.x;
    const int lane = tid & 63;
    const int w    = tid >> 6;
    const int n    = lane & 15;
    const int quad = lane >> 4;

    const int bid = blockIdx.x;        // 0..255
    const int s   = blockIdx.y;
    const int g  = bid & 7;
    const int jj = bid >> 3;           // 0..31
    const int h  = g * 4 + (jj & 3);
    const int qt = jj >> 2;            // 0..7, 128-row q tiles

    const int qr0 = qt * 128 + w * 16; // m-tile 0 base; m-tile 1 = +64

    bf16x8 qf[2][4];
#pragma unroll
    for (int mt = 0; mt < 2; mt++) {
        const __bf16* qp = qb + (long)(qr0 + mt * 64 + n) * 4096 + h * 128 + quad * 8;
        qf[mt][0] = *(const bf16x8*)(qp);
        qf[mt][1] = *(const bf16x8*)(qp + 32);
        qf[mt][2] = *(const bf16x8*)(qp + 64);
        qf[mt][3] = *(const bf16x8*)(qp + 96);
    }

    f32x4 O[2][8];
    const f32x4 fzero = {0.f, 0.f, 0.f, 0.f};
#pragma unroll
    for (int mt = 0; mt < 2; mt++)
#pragma unroll
        for (int dt = 0; dt < 8; dt++) O[mt][dt] = fzero;
    float l_loc[2] = {0.f, 0.f};       // lane-local: lane n16 owns q-row qr0+mt*64+n

    const int ntot = 34 + 2 * qt;      // even
    const int half = ntot >> 1;
    const int tbeg = s ? half : 0;
    const int tend = s ? ntot : half;

    const int krr = tid >> 4, kc8 = (tid & 15) * 8;
    const int vrr = tid >> 3, vc8 = (tid & 7) * 8;
    const __bf16* kp = kb + g * 128 + (long)(tbeg * 64 + krr) * 1024 + kc8;
    const __bf16* vp = vtg + (long)g * 128 * 3072 + (long)vrr * 3072 + tbeg * 64 + vc8;

    for (int tt = tbeg; tt < tend; tt++) {
#pragma unroll
        for (int i = 0; i < 4; i++)
            *(bf16x8*)&KS(krr + i * 16, kc8) = *(const bf16x8*)(kp + (long)i * 16 * 1024);
#pragma unroll
        for (int i = 0; i < 4; i++)
            *(bf16x8*)&Vs[vrr + i * 32][vc8] = *(const bf16x8*)(vp + (long)i * 32 * 3072);
        kp += 64 * 1024;
        vp += 64;
        __syncthreads();

        // S^T = K Q^T: A = K-frag, B = Q-frag (identical lane layouts).
        // Result: col(lane&15) = q-row, row(quad*4+r) = key t.
        f32x4 S[2][4];
#pragma unroll
        for (int nt = 0; nt < 4; nt++) {
            f32x4 a0 = fzero, a1 = fzero;
#pragma unroll
            for (int ks = 0; ks < 4; ks++) {
                bf16x8 kf = *(const bf16x8*)&KS(nt * 16 + n, ks * 32 + quad * 8);
                a0 = MFMA16(kf, qf[0][ks], a0);
                a1 = MFMA16(kf, qf[1][ks], a1);
            }
            S[0][nt] = a0;
            S[1][nt] = a1;
        }

        if (tt >= ntot - 2) {   // diagonal band spans the last two tiles
            const int t0 = tt * 64;
#pragma unroll
            for (int mt = 0; mt < 2; mt++) {
                const int lim = 2048 + qr0 + mt * 64 + n;   // q-row = lane index
#pragma unroll
                for (int nt = 0; nt < 4; nt++)
#pragma unroll
                    for (int r = 0; r < 4; r++) {
                        int t = t0 + nt * 16 + quad * 4 + r;
                        if (t > lim) S[mt][nt][r] = -1e30f;
                    }
            }
        }

        __syncthreads();   // all Ks reads done; Ps may overwrite

        // fixed-shift softmax; row-sum is lane-local (lane owns its q-row)
#pragma unroll
        for (int mt = 0; mt < 2; mt++)
#pragma unroll
            for (int nt = 0; nt < 4; nt++)
#pragma unroll
                for (int r = 0; r < 4; r++) {
                    float p = __expf(S[mt][nt][r] - MSTATIC);
                    S[mt][nt][r] = p;
                    l_loc[mt] += p;
                }

        // P -> LDS: packed b64 writes (4 consecutive t per (mt,nt))
#pragma unroll
        for (int mt = 0; mt < 2; mt++)
#pragma unroll
            for (int nt = 0; nt < 4; nt++) {
                bf16x4 pk;
#pragma unroll
                for (int r = 0; r < 4; r++) pk[r] = (__bf16)S[mt][nt][r];
                *(bf16x4*)&PS(w, mt * 16 + n, nt * 16 + quad * 4) = pk;
            }

        bf16x8 pa[2][2];
#pragma unroll
        for (int mt = 0; mt < 2; mt++)
#pragma unroll
            for (int kg = 0; kg < 2; kg++)
                pa[mt][kg] = *(const bf16x8*)&PS(w, mt * 16 + n, kg * 32 + quad * 8);

#pragma unroll
        for (int dt = 0; dt < 8; dt++) {
            bf16x8 vf0 = *(const bf16x8*)&Vs[dt * 16 + n][quad * 8];
            bf16x8 vf1 = *(const bf16x8*)&Vs[dt * 16 + n][32 + quad * 8];
#pragma unroll
            for (int mt = 0; mt < 2; mt++) {
                f32x4 acc = O[mt][dt];
                acc = MFMA16(pa[mt][0], vf0, acc);
                acc = MFMA16(pa[mt][1], vf1, acc);
                O[mt][dt] = acc;
            }
        }
        __syncthreads();
    }

    // row-sum: reduce across the 4 quads (lane already holds its row's partial)
#pragma unroll
    for (int mt = 0; mt < 2; mt++) {
        float sm = l_loc[mt];
        sm += __shfl_xor(sm, 16);
        sm += __shfl_xor(sm, 32);
        l_loc[mt] = sm;
    }

    __bf16* Op = s ? Opart1 : Opart0;
    const long tb = (long)(h * 8 + qt) * 128 * 128;
#pragma unroll
    for (int mt = 0; mt < 2; mt++)
#pragma unroll
        for (int dt = 0; dt < 8; dt++)
#pragma unroll
            for (int r = 0; r < 4; r++)
                Op[tb + (long)(mt * 64 + w * 16 + quad * 4 + r) * 128 + dt * 16 + n] =
                    (__bf16)O[mt][dt][r];
    if (quad == 0) {
        const int lb = (s * 256 + h * 8 + qt) * 128 + w * 16;
#pragma unroll
        for (int mt = 0; mt < 2; mt++)
            lsum[lb + mt * 64 + n] = l_loc[mt];
    }
#undef KS
#undef PS
}

// ---------------------------------------------------------------------------
// Additive merge of split-K partials -> normalized bf16 attn-out.
// ---------------------------------------------------------------------------
__global__ __launch_bounds__(256) void flash_merge(const __bf16* __restrict__ O0,
                                                   const __bf16* __restrict__ O1,
                                                   const float* __restrict__ lsum,
                                                   __bf16* __restrict__ ob) {
    const int bx = blockIdx.x;         // 512: (h, qt, half64)
    const int h   = bx >> 4;
    const int r6  = bx & 15;
    const int qt  = r6 >> 1;
    const int sub = r6 & 1;
    const int row  = threadIdx.x >> 2;
    const int cseg = (threadIdx.x & 3) * 32;
    const int mrow = sub * 64 + row;

    const int tilei = h * 8 + qt;
    float inv = 1.0f / (lsum[tilei * 128 + mrow] + lsum[(256 + tilei) * 128 + mrow]);

    const long src = (long)tilei * 128 * 128 + (long)mrow * 128 + cseg;
    __bf16* dst = ob + (long)(qt * 128 + mrow) * 4096 + h * 128 + cseg;
#pragma unroll
    for (int j = 0; j < 4; j++) {
        bf16x8 x0 = *(const bf16x8*)(O0 + src + j * 8);
        bf16x8 x1 = *(const bf16x8*)(O1 + src + j * 8);
        bf16x8 o;
#pragma unroll
        for (int k = 0; k < 8; k++)
            o[k] = (__bf16)(((float)x0[k] + (float)x1[k]) * inv);
        *(bf16x8*)(dst + j * 8) = o;
    }
}

// ---------------------------------------------------------------------------
extern "C" void kernel_launch(void* const* d_in, const int* in_sizes, int n_in,
                              void* d_out, int out_size, void* d_ws, size_t ws_size,
                              hipStream_t stream) {
    const float* hidden = (const float*)d_in[0];
    const float* target = (const float*)d_in[1];
    const float* cosb   = (const float*)d_in[2];
    const float* sinb   = (const float*)d_in[3];
    const float* wq = (const float*)d_in[5];
    const float* wk = (const float*)d_in[6];
    const float* wv = (const float*)d_in[7];
    const float* wo = (const float*)d_in[8];
    const float* qw = (const float*)d_in[9];
    const float* kw = (const float*)d_in[10];
    float* out = (float*)d_out;

    // 40 MB workspace overlays (launch order guarantees safety). qbf and the
    // z=0 wo-partial live in d_out (dead region until the final add).
    char* ws = (char*)d_ws;
    const long MB = 1 << 20;
    __bf16* hidb = (__bf16*)(ws);             // @0..4    (dead after kvq)
    __bf16* tgtb = (__bf16*)(ws + 4 * MB);    // @4..12   (dead after kvq)
    __bf16* wkb  = (__bf16*)(ws + 12 * MB);   // @12..16  (dead after kvq)
    __bf16* wvb  = (__bf16*)(ws + 16 * MB);   // @16..20  (dead after kvq)
    __bf16* kbf  = (__bf16*)(ws + 20 * MB);   // @20..26  (dead after flash)
    __bf16* vbf  = (__bf16*)(ws + 26 * MB);   // @26..32  (dead after transpose)
    __bf16* vtg  = (__bf16*)(ws + 32 * MB);   // @32..38  (dead after flash)
    float*  lbuf = (float*)(ws);              // @0..0.25 (post-kvq; dead after merge)
    __bf16* Op0  = (__bf16*)(ws + 4 * MB);    // @4..12   (post-kvq; dead after merge)
    __bf16* Op1  = (__bf16*)(ws + 12 * MB);   // @12..20  (post-kvq; dead after merge)
    __bf16* attnb= (__bf16*)(ws + 20 * MB);   // @20..28  (post-flash)
    float*  po1  = (float*)(ws + 4 * MB);     // @4..12   (post-merge)
    float*  po2  = (float*)(ws + 12 * MB);    // @12..20  (post-merge)
    float*  po3  = (float*)(ws + 28 * MB);    // @28..36  (post-flash)
    __bf16* qbf  = (__bf16*)d_out;            // 8MB: q / dead after flash

    dim3 blk(256);

    // activations + k/v weights -> bf16
    conv4_f32_bf16<<<dim3(1024, 4), blk, 0, stream>>>(
        hidden, hidb, (1024 * 2048) / 4, target, tgtb, (2048 * 2048) / 4,
        wk, wkb, (1024 * 2048) / 4, wv, wvb, (1024 * 2048) / 4);

    // all three projections, one launch, 640 blocks all resident
    gemm_kvq<<<640, blk, 0, stream>>>(tgtb, hidb, wkb, wvb, wq, kbf, vbf, qbf);

    // fused RMSNorm + RoPE (q and k)
    rmsnorm_rope2<<<dim3(8192, 2), blk, 0, stream>>>(qbf, qw, kbf, kw, cosb, sinb);

    // V transpose -> [g][d][t]
    transpose_v<<<dim3(48, 2, 8), blk, 0, stream>>>(vbf, vtg);

    // split-K flash attention (512 blocks, 128 q-rows each) + additive merge
    flash_attn_splitk<<<dim3(256, 2), blk, 0, stream>>>(qbf, kbf, vtg, Op0, Op1, lbuf);
    flash_merge<<<512, blk, 0, stream>>>(Op0, Op1, lbuf, attnb);

    // output projection: 256x64 fb tiles, split-K=4 (512 blocks) + reduce
    gemm_wo4<<<512, blk, 0, stream>>>(attnb, wo, out, po1, po2, po3);
    add4_wo<<<1024, blk, 0, stream>>>(out, po1, po2, po3, (1024 * 2048) / 4);
}